// Round 6
// baseline (1245.888 us; speedup 1.0000x reference)
//
#include <hip/hip_runtime.h>

#define BB 16
#define NN 8192
#define SS 512
#define N3 (3 * NN)  // 24576 elements per batch per tensor
#define KD 14        // per-lane KNN list depth (see knn comment)
#define KNN_BLOCKS 128

typedef unsigned short u16;
typedef unsigned int u32;
typedef unsigned long long u64;
typedef float v2f __attribute__((ext_vector_type(2)));

// Packed fp32 ops (VOP3P, 2 points/inst). Per-half rounding is IEEE rn —
// bit-identical to scalar __fadd_rn/__fmul_rn.
__device__ __forceinline__ v2f pk_add(v2f a, v2f b) {
  v2f r;
  asm("v_pk_add_f32 %0, %1, %2" : "=v"(r) : "v"(a), "v"(b));
  return r;
}
__device__ __forceinline__ v2f pk_mul(v2f a, v2f b) {
  v2f r;
  asm("v_pk_mul_f32 %0, %1, %2" : "=v"(r) : "v"(a), "v"(b));
  return r;
}

// u64 max step over a DPP lane-shift: shift both 32-bit halves with the same
// control (old=0 is the identity for max of our non-negative keys), then one
// v_cmp_lt_u64 + 2 cndmask. Stays entirely on the VALU pipe — r15's lesson:
// __shfl_xor is ds_bpermute (LDS pipe, ~40+cy dependent) and 9 such steps on
// the serial path cost ~+500cy/iter (544 -> 658 us).
template <int CTRL>
__device__ __forceinline__ u64 dpp_maxk(u64 k) {
  u32 lo = (u32)k, hi = (u32)(k >> 32);
  u32 slo = (u32)__builtin_amdgcn_update_dpp(0, (int)lo, CTRL, 0xf, 0xf, false);
  u32 shi = (u32)__builtin_amdgcn_update_dpp(0, (int)hi, CTRL, 0xf, 0xf, false);
  u64 s = ((u64)shi << 32) | (u64)slo;
  return (s > k) ? s : k;
}
__device__ __forceinline__ u64 maxk(u64 a, u64 b) { return (a > b) ? a : b; }

// ---------------------------------------------------------------------------
// K0: precompute per-point float4 {x,y,z,|q|^2} for xyz and {x,y,z,0} for
// l0_points into workspace (|q|^2 uses the EXACT rn tree -> bits unchanged
// downstream). Also zeroes the 16 per-batch progress flags each replay.
// ---------------------------------------------------------------------------
__global__ __launch_bounds__(256) void k_prep(const float* __restrict__ xyz,
                                              const float* __restrict__ pts,
                                              float4* __restrict__ xyz4,
                                              float4* __restrict__ pts4,
                                              u32* __restrict__ progress) {
  if (blockIdx.x == 0 && threadIdx.x < BB)
    __hip_atomic_store(progress + threadIdx.x, 0u, __ATOMIC_RELAXED,
                       __HIP_MEMORY_SCOPE_AGENT);
  int i = blockIdx.x * 256 + threadIdx.x;  // < BB*NN
  int b = i >> 13, n = i & (NN - 1);
  const float* xb = xyz + b * N3;
  float x = xb[n], y = xb[NN + n], z = xb[2 * NN + n];
  float w = __fadd_rn(__fadd_rn(__fmul_rn(x, x), __fmul_rn(y, y)), __fmul_rn(z, z));
  xyz4[i] = make_float4(x, y, z, w);
  const float* pb = pts + b * N3;
  pts4[i] = make_float4(pb[n], pb[NN + n], pb[2 * NN + n], 0.f);
}

// ---------------------------------------------------------------------------
// K1 (r19): FPS + KNN fused, overlapped via intra-kernel producer/consumer
// flags. r18 post-mortem: mega ran 834us (vs 515 predicted) — two unpriced
// mechanisms: (1) per-iteration s_waitcnt vmcnt(0) draining AGENT-scope
// (coherence-point, non-posted) coord stores serialized lane0 ~600cy x 512
// iters; (2) 1024 acquire-spinning waves at s_sleep(2) = ~20k polls/us of
// L1-invalidate+L3 traffic congesting the same coherence path. r19 fixes:
//   - publish cadence 8: coord stores stay fire-and-forget every iter; drain
//     + flag only at it%8==0 (63 drains, youngest outstanding store ~2400cy
//     old -> drain ~free). Consumer wait thresholds are multiples of 8,
//     exactly matching published values.
//   - block-level spin: consumers b-major (block cb: batch b=cb&15, s-range
//     (cb>>4)*64..+63, 8 waves x 8 passes). Only t==0 polls (128 pollers,
//     s_sleep(8)); other waves park at __syncthreads. ~100x less poll traffic.
// Coherence: coords + flags via agent-scope atomics as r18 (correct there).
// Deadlock-free by residency: 144 blocks x ~98KB LDS = 1 block/CU <= 256 CUs.
// FPS core r16 (bit-exact, see notes); KNN core r17 float4 path.
// ---------------------------------------------------------------------------
__global__ __attribute__((amdgpu_flat_work_group_size(512, 512),
                          amdgpu_waves_per_eu(2, 2)))
void k_fps_knn(const float* __restrict__ xyz, const float4* __restrict__ xyz4,
               float* __restrict__ out_kp, u16* __restrict__ knn,
               u32* __restrict__ progress) {
  __shared__ float sxyz[NN * 3];  // [idx][x,y,z] (FPS blocks only)
  __shared__ u64 rkey[2][8];
  int t = threadIdx.x;
  int lane = t & 63, w = t >> 6;
  if (blockIdx.x < BB) {
    // ---------------- FPS producer ----------------
    int b = blockIdx.x;
    const float* base = xyz + b * N3;
    v2f px[8], py[8], pz[8], dm[8];
#pragma unroll
    for (int j = 0; j < 8; ++j) {
      int n0 = j * 1024 + t, n1 = n0 + 512;  // coalesced, disjoint cover
      px[j] = v2f{base[n0], base[n1]};
      py[j] = v2f{base[NN + n0], base[NN + n1]};
      pz[j] = v2f{base[2 * NN + n0], base[2 * NN + n1]};
      dm[j] = v2f{1e10f, 1e10f};
      sxyz[n0 * 3 + 0] = px[j].x;  // stage AoS copy for center re-loads
      sxyz[n0 * 3 + 1] = py[j].x;
      sxyz[n0 * 3 + 2] = pz[j].x;
      sxyz[n1 * 3 + 0] = px[j].y;
      sxyz[n1 * 3 + 1] = py[j].y;
      sxyz[n1 * 3 + 2] = pz[j].y;
    }
#pragma unroll
    for (int j = 0; j < 8; ++j) {
      // Opaque def: blocks rematerialization of the global loads.
      asm volatile("" : "+v"(px[j]), "+v"(py[j]), "+v"(pz[j]));
    }
    float cx = base[0], cy = base[NN], cz = base[2 * NN];
    u32 tb = (u32)(NN - t);  // cand = NN - gidx (1..8192; 0=none)
    for (int it = 0; it < SS; ++it) {
      // publish: every 8th iter, drain outstanding coord stores (youngest is
      // ~1 iter = ~2400cy old -> wait ~free) then flag keypoints [0,it).
      // Coord stores for keypoint it are fire-and-forget (no wait here).
      if (t == 0) {
        if ((it & 7) == 0 && it > 0) {
          asm volatile("s_waitcnt vmcnt(0)" ::: "memory");
          __hip_atomic_store(progress + b, (u32)it, __ATOMIC_RELAXED,
                             __HIP_MEMORY_SCOPE_AGENT);
        }
        __hip_atomic_store(out_kp + b * 1536 + it, cx, __ATOMIC_RELAXED,
                           __HIP_MEMORY_SCOPE_AGENT);
        __hip_atomic_store(out_kp + b * 1536 + SS + it, cy, __ATOMIC_RELAXED,
                           __HIP_MEMORY_SCOPE_AGENT);
        __hip_atomic_store(out_kp + b * 1536 + 2 * SS + it, cz, __ATOMIC_RELAXED,
                           __HIP_MEMORY_SCOPE_AGENT);
      }
      // negated center, broadcast to both halves (a + (-c) == a - c exactly)
      v2f ncx = v2f{-cx, -cx}, ncy = v2f{-cy, -cy}, ncz = v2f{-cz, -cz};
      float vmax = 0.0f;
#pragma unroll
      for (int j = 0; j < 8; ++j) {
        v2f dx = pk_add(px[j], ncx);
        v2f dy = pk_add(py[j], ncy);
        v2f dz = pk_add(pz[j], ncz);
        v2f xx = pk_mul(dx, dx);
        v2f yy = pk_mul(dy, dy);
        v2f s = pk_add(xx, yy);
        v2f zz = pk_mul(dz, dz);
        v2f d = pk_add(s, zz);  // ((dx^2+dy^2)+dz^2), numpy tree per half
        float a0 = fminf(dm[j].x, d.x);
        float a1 = fminf(dm[j].y, d.y);
        dm[j].x = a0;
        dm[j].y = a1;
        vmax = fmaxf(vmax, fmaxf(a0, a1));  // max3-foldable
      }
      // thread-local find vs OWN max: exact bit-equality (vmax IS one of this
      // thread's dm values). Descending gidx -> LAST write = lowest gidx.
      u32 cand = 0;
#pragma unroll
      for (int j = 7; j >= 0; --j) {
        u32 v1 = tb - (u32)(j * 1024 + 512);  // .y half (higher gidx)
        u32 v0 = tb - (u32)(j * 1024);        // .x half
        cand = (dm[j].y == vmax) ? v1 : cand;
        cand = (dm[j].x == vmax) ? v0 : cand;
      }
      // 6-step DPP u64 max chain -> lane63 = wave best. VALU pipe only.
      u64 key = ((u64)__float_as_uint(vmax) << 32) | cand;
      key = dpp_maxk<0x111>(key);  // row_shr:1
      key = dpp_maxk<0x112>(key);  // row_shr:2
      key = dpp_maxk<0x114>(key);  // row_shr:4
      key = dpp_maxk<0x118>(key);  // row_shr:8
      key = dpp_maxk<0x142>(key);  // row_bcast:15
      key = dpp_maxk<0x143>(key);  // row_bcast:31
      int pb = it & 1;  // parity double-buffer: safe with one barrier/iter
      if (lane == 63) rkey[pb][w] = key;
      __syncthreads();  // the only barrier per iteration
      // block reduce: every thread broadcast-reads all 8 wave keys + redundant
      // VALU tree (no cross-lane ops in this phase).
      u64 k0 = rkey[pb][0], k1 = rkey[pb][1];
      u64 k2 = rkey[pb][2], k3 = rkey[pb][3];
      u64 k4 = rkey[pb][4], k5 = rkey[pb][5];
      u64 k6 = rkey[pb][6], k7 = rkey[pb][7];
      u64 kg = maxk(maxk(maxk(k0, k1), maxk(k2, k3)),
                    maxk(maxk(k4, k5), maxk(k6, k7)));
      int far = NN - (int)(u32)(kg & 0xffffffffu);
      // broadcast ds_read of the winner's coords (all lanes same address)
      cx = sxyz[far * 3 + 0];
      cy = sxyz[far * 3 + 1];
      cz = sxyz[far * 3 + 2];
    }
    // keypoints 504..511 stored inside their iters; drain + final flag
    if (t == 0) {
      asm volatile("s_waitcnt vmcnt(0)" ::: "memory");
      __hip_atomic_store(progress + b, (u32)SS, __ATOMIC_RELAXED,
                         __HIP_MEMORY_SCOPE_AGENT);
    }
  } else {
    // ---------------- KNN consumer ----------------
    // b-major: block cb -> batch b = cb&15, s-chunk j = cb>>4 (s in
    // [64j, 64j+64)). 8 passes x 8 waves, s = 64j + 8p + w — monotone in
    // time, matching production order (~1 keypoint/us/batch). Only t==0
    // polls; other waves park at the barrier.
    int cb = blockIdx.x - BB;
    int b = cb & 15, j = cb >> 4;
    const float4* base4 = xyz4 + (b << 13);
    for (int p = 0; p < 8; ++p) {
      int sbase = j * 64 + p * 8;
      if (t == 0) {
        while (__hip_atomic_load(progress + b, __ATOMIC_ACQUIRE,
                                 __HIP_MEMORY_SCOPE_AGENT) < (u32)(sbase + 8))
          __builtin_amdgcn_s_sleep(8);
      }
      __syncthreads();  // park the other 7 waves while t0 spins
      int s = sbase + w;
      float ax = __hip_atomic_load(out_kp + b * 1536 + s, __ATOMIC_RELAXED,
                                   __HIP_MEMORY_SCOPE_AGENT);
      float ay = __hip_atomic_load(out_kp + b * 1536 + SS + s, __ATOMIC_RELAXED,
                                   __HIP_MEMORY_SCOPE_AGENT);
      float az = __hip_atomic_load(out_kp + b * 1536 + 2 * SS + s, __ATOMIC_RELAXED,
                                   __HIP_MEMORY_SCOPE_AGENT);
      float aw = __fadd_rn(__fadd_rn(__fmul_rn(ax, ax), __fmul_rn(ay, ay)),
                           __fmul_rn(az, az));
      u64 arr[KD];
#pragma unroll
      for (int i = 0; i < KD; ++i) arr[i] = ~0ull;
      for (int c = 0; c < 128; ++c) {
        int n = c * 64 + lane;
        float4 q = base4[n];  // one dwordx4, coalesced
        float dot = __fadd_rn(__fadd_rn(__fmul_rn(ax, q.x), __fmul_rn(ay, q.y)),
                              __fmul_rn(az, q.z));
        float d = __fsub_rn(__fadd_rn(aw, q.w), __fmul_rn(2.0f, dot));
        u32 ub = __float_as_uint(d);
        ub ^= (ub & 0x80000000u) ? 0xFFFFFFFFu : 0x80000000u;  // order-preserving
        u64 key = ((u64)ub << 32) | (u32)n;
        if (key < arr[KD - 1]) {  // sorted insert, CSE'd conditions
          bool cg[KD];
#pragma unroll
          for (int i = 0; i < KD; ++i) cg[i] = arr[i] > key;
#pragma unroll
          for (int i = KD - 1; i >= 1; --i)
            arr[i] = cg[i - 1] ? arr[i - 1] : (cg[i] ? key : arr[i]);
          arr[0] = cg[0] ? key : arr[0];
        }
      }
      // merge 64 sorted lists: 24 x (wave-min of heads, winner pops).
      u64 mine = 0;
      for (int it = 0; it < 24; ++it) {
        u64 m = arr[0];
#pragma unroll
        for (int off = 1; off < 64; off <<= 1) {
          u64 o = __shfl_xor(m, off, 64);
          m = (o < m) ? o : m;
        }
        if (lane == it) mine = m;
        if (arr[0] == m) {
#pragma unroll
          for (int i = 0; i < KD - 1; ++i) arr[i] = arr[i + 1];
          arr[KD - 1] = ~0ull;
        }
      }
      int row = b * SS + s;
      if (lane < 24) knn[row * 24 + lane] = (u16)(mine & 0xFFFFu);
    }
  }
}

// ---------------------------------------------------------------------------
// Fallback solo kernels (workspace too small for float4/flags): r16 k_fps +
// r17 k_knn scalar path, serial. Not used when ws suffices.
// ---------------------------------------------------------------------------
__global__ __attribute__((amdgpu_flat_work_group_size(512, 512),
                          amdgpu_waves_per_eu(2, 2)))
void k_fps_solo(const float* __restrict__ xyz, float* __restrict__ out_kp) {
  __shared__ float sxyz[NN * 3];
  __shared__ int sIdx[SS];
  __shared__ u64 rkey[2][8];
  int b = blockIdx.x, t = threadIdx.x;
  const float* base = xyz + b * N3;
  v2f px[8], py[8], pz[8], dm[8];
#pragma unroll
  for (int j = 0; j < 8; ++j) {
    int n0 = j * 1024 + t, n1 = n0 + 512;
    px[j] = v2f{base[n0], base[n1]};
    py[j] = v2f{base[NN + n0], base[NN + n1]};
    pz[j] = v2f{base[2 * NN + n0], base[2 * NN + n1]};
    dm[j] = v2f{1e10f, 1e10f};
    sxyz[n0 * 3 + 0] = px[j].x;
    sxyz[n0 * 3 + 1] = py[j].x;
    sxyz[n0 * 3 + 2] = pz[j].x;
    sxyz[n1 * 3 + 0] = px[j].y;
    sxyz[n1 * 3 + 1] = py[j].y;
    sxyz[n1 * 3 + 2] = pz[j].y;
  }
#pragma unroll
  for (int j = 0; j < 8; ++j) asm volatile("" : "+v"(px[j]), "+v"(py[j]), "+v"(pz[j]));
  float cx = base[0], cy = base[NN], cz = base[2 * NN];
  int far = 0;
  int lane = t & 63, w = t >> 6;
  u32 tb = (u32)(NN - t);
  for (int it = 0; it < SS; ++it) {
    if (t == 0) sIdx[it] = far;
    v2f ncx = v2f{-cx, -cx}, ncy = v2f{-cy, -cy}, ncz = v2f{-cz, -cz};
    float vmax = 0.0f;
#pragma unroll
    for (int j = 0; j < 8; ++j) {
      v2f dx = pk_add(px[j], ncx);
      v2f dy = pk_add(py[j], ncy);
      v2f dz = pk_add(pz[j], ncz);
      v2f xx = pk_mul(dx, dx);
      v2f yy = pk_mul(dy, dy);
      v2f s = pk_add(xx, yy);
      v2f zz = pk_mul(dz, dz);
      v2f d = pk_add(s, zz);
      float a0 = fminf(dm[j].x, d.x);
      float a1 = fminf(dm[j].y, d.y);
      dm[j].x = a0;
      dm[j].y = a1;
      vmax = fmaxf(vmax, fmaxf(a0, a1));
    }
    u32 cand = 0;
#pragma unroll
    for (int j = 7; j >= 0; --j) {
      u32 v1 = tb - (u32)(j * 1024 + 512);
      u32 v0 = tb - (u32)(j * 1024);
      cand = (dm[j].y == vmax) ? v1 : cand;
      cand = (dm[j].x == vmax) ? v0 : cand;
    }
    u64 key = ((u64)__float_as_uint(vmax) << 32) | cand;
    key = dpp_maxk<0x111>(key);
    key = dpp_maxk<0x112>(key);
    key = dpp_maxk<0x114>(key);
    key = dpp_maxk<0x118>(key);
    key = dpp_maxk<0x142>(key);
    key = dpp_maxk<0x143>(key);
    int pb = it & 1;
    if (lane == 63) rkey[pb][w] = key;
    __syncthreads();
    u64 k0 = rkey[pb][0], k1 = rkey[pb][1];
    u64 k2 = rkey[pb][2], k3 = rkey[pb][3];
    u64 k4 = rkey[pb][4], k5 = rkey[pb][5];
    u64 k6 = rkey[pb][6], k7 = rkey[pb][7];
    u64 kg = maxk(maxk(maxk(k0, k1), maxk(k2, k3)),
                  maxk(maxk(k4, k5), maxk(k6, k7)));
    far = NN - (int)(u32)(kg & 0xffffffffu);
    cx = sxyz[far * 3 + 0];
    cy = sxyz[far * 3 + 1];
    cz = sxyz[far * 3 + 2];
  }
  __syncthreads();
  for (int i = t; i < SS; i += 512) {
    int id = sIdx[i];
    out_kp[b * 1536 + i] = base[id];
    out_kp[b * 1536 + SS + i] = base[NN + id];
    out_kp[b * 1536 + 2 * SS + i] = base[2 * NN + id];
  }
}

__global__ __launch_bounds__(256) void k_knn_solo(const float* __restrict__ xyz,
                                                  const float* __restrict__ kp,
                                                  u16* __restrict__ knn) {
  int t = threadIdx.x;
  int row = blockIdx.x * 4 + (t >> 6);
  int lane = t & 63;
  int b = row >> 9, s = row & (SS - 1);
  const float* base = xyz + b * N3;
  float ax = kp[b * 1536 + s];
  float ay = kp[b * 1536 + SS + s];
  float az = kp[b * 1536 + 2 * SS + s];
  float aw = __fadd_rn(__fadd_rn(__fmul_rn(ax, ax), __fmul_rn(ay, ay)), __fmul_rn(az, az));
  u64 arr[KD];
#pragma unroll
  for (int i = 0; i < KD; ++i) arr[i] = ~0ull;
  for (int c = 0; c < 128; ++c) {
    int n = c * 64 + lane;
    float qx = base[n], qy = base[NN + n], qz = base[2 * NN + n];
    float qw = __fadd_rn(__fadd_rn(__fmul_rn(qx, qx), __fmul_rn(qy, qy)), __fmul_rn(qz, qz));
    float dot = __fadd_rn(__fadd_rn(__fmul_rn(ax, qx), __fmul_rn(ay, qy)), __fmul_rn(az, qz));
    float d = __fsub_rn(__fadd_rn(aw, qw), __fmul_rn(2.0f, dot));
    u32 ub = __float_as_uint(d);
    ub ^= (ub & 0x80000000u) ? 0xFFFFFFFFu : 0x80000000u;
    u64 key = ((u64)ub << 32) | (u32)n;
    if (key < arr[KD - 1]) {
      bool cg[KD];
#pragma unroll
      for (int i = 0; i < KD; ++i) cg[i] = arr[i] > key;
#pragma unroll
      for (int i = KD - 1; i >= 1; --i)
        arr[i] = cg[i - 1] ? arr[i - 1] : (cg[i] ? key : arr[i]);
      arr[0] = cg[0] ? key : arr[0];
    }
  }
  u64 mine = 0;
  for (int it = 0; it < 24; ++it) {
    u64 m = arr[0];
#pragma unroll
    for (int off = 1; off < 64; off <<= 1) {
      u64 o = __shfl_xor(m, off, 64);
      m = (o < m) ? o : m;
    }
    if (lane == it) mine = m;
    if (arr[0] == m) {
#pragma unroll
      for (int i = 0; i < KD - 1; ++i) arr[i] = arr[i + 1];
      arr[KD - 1] = ~0ull;
    }
  }
  if (lane < 24) knn[row * 24 + lane] = (u16)(mine & 0xFFFFu);
}

// ---------------------------------------------------------------------------
// K3 (r17, unchanged): fused base-SA + multi-scale MLPs. blockIdx.y = 0 ->
// base (feat [rel_xyz|pts] 6->64 relu -> 64->128, K=16, out ch 0..127);
// blockIdx.y = 1..3 -> ms scale y-1 (rel_xyz 3->64 relu -> 64->128, K=8y,
// out ch 128y..128y+127). Branch is block-uniform. Staging gathers via
// float4 (USE4). Per-wave h2: thread owns 2 out channels, W2 rows in
// registers, h1 read as wave-uniform float4 broadcast.
// ---------------------------------------------------------------------------
template <int USE4>
__global__ __launch_bounds__(256) void k_mlp(
    const float* __restrict__ xyz, const float* __restrict__ pts,
    const float4* __restrict__ xyz4, const float4* __restrict__ pts4,
    const float* __restrict__ kp, const u16* __restrict__ knn,
    const float* __restrict__ W1, const float* __restrict__ b1,
    const float* __restrict__ W2, const float* __restrict__ b2,
    const float* __restrict__ msW1, const float* __restrict__ msb1,
    const float* __restrict__ msW2, const float* __restrict__ msb2,
    float* __restrict__ out) {
  __shared__ float smem[6688];
  int t = threadIdx.x, lane = t & 63, w = t >> 6;
  int b = blockIdx.x >> 6, s0 = (blockIdx.x & 63) * 8;
  if (blockIdx.y == 0) {
    float* sW1T = smem;
    float* sb1 = smem + 384;
    float* sfeat = smem + 448;
    float* sh1 = smem + 832;
    for (int i = t; i < 384; i += 256) {
      int o = i / 6, c = i - o * 6;
      sW1T[c * 64 + o] = W1[i];
    }
    if (t < 64) sb1[t] = b1[t];
    float wgtA[64], wgtB[64];
#pragma unroll
    for (int j = 0; j < 64; ++j) {
      wgtA[j] = W2[lane * 64 + j];
      wgtB[j] = W2[(lane + 64) * 64 + j];
    }
    float b2A = b2[lane], b2B = b2[lane + 64];
    __syncthreads();
    for (int g = 0; g < 2; ++g) {
      if (t < 128) {  // 64 (rr,k) pairs x 2 halves: h=0 xyz, h=1 pts
        int p = t >> 1, h = t & 1;
        int rr = p >> 4, k = p & 15;
        int s = s0 + g * 4 + rr, row = b * SS + s;
        int id = knn[row * 24 + k];
        float* f = &sfeat[rr * 96 + k * 6];
        if (h == 0) {
          float qx, qy, qz;
          if constexpr (USE4) {
            float4 q = xyz4[(b << 13) + id];
            qx = q.x; qy = q.y; qz = q.z;
          } else {
            qx = xyz[b * N3 + id];
            qy = xyz[b * N3 + NN + id];
            qz = xyz[b * N3 + 2 * NN + id];
          }
          f[0] = __fsub_rn(qx, kp[b * 1536 + s]);
          f[1] = __fsub_rn(qy, kp[b * 1536 + SS + s]);
          f[2] = __fsub_rn(qz, kp[b * 1536 + 2 * SS + s]);
        } else {
          float px_, py_, pz_;
          if constexpr (USE4) {
            float4 q = pts4[(b << 13) + id];
            px_ = q.x; py_ = q.y; pz_ = q.z;
          } else {
            px_ = pts[b * N3 + id];
            py_ = pts[b * N3 + NN + id];
            pz_ = pts[b * N3 + 2 * NN + id];
          }
          f[3] = px_;
          f[4] = py_;
          f[5] = pz_;
        }
      }
      __syncthreads();
#pragma unroll
      for (int m = 0; m < 16; ++m) {
        int u = m * 256 + t;
        int rr = u >> 10, rem = u & 1023, k = rem >> 6, o = rem & 63;
        float acc = sb1[o];
#pragma unroll
        for (int c = 0; c < 6; ++c) acc = fmaf(sfeat[rr * 96 + k * 6 + c], sW1T[c * 64 + o], acc);
        sh1[rr * 1024 + k * 64 + o] = fmaxf(acc, 0.f);
      }
      __syncthreads();
      float bestA = -1e30f, bestB = -1e30f;
#pragma unroll
      for (int k = 0; k < 16; ++k) {
        const float4* h4 = (const float4*)&sh1[w * 1024 + k * 64];
        float a0 = 0.f, a1 = 0.f;
#pragma unroll
        for (int j = 0; j < 16; ++j) {
          float4 hv = h4[j];
          a0 = fmaf(hv.x, wgtA[4 * j], a0);
          a0 = fmaf(hv.y, wgtA[4 * j + 1], a0);
          a0 = fmaf(hv.z, wgtA[4 * j + 2], a0);
          a0 = fmaf(hv.w, wgtA[4 * j + 3], a0);
          a1 = fmaf(hv.x, wgtB[4 * j], a1);
          a1 = fmaf(hv.y, wgtB[4 * j + 1], a1);
          a1 = fmaf(hv.z, wgtB[4 * j + 2], a1);
          a1 = fmaf(hv.w, wgtB[4 * j + 3], a1);
        }
        bestA = fmaxf(bestA, a0);
        bestB = fmaxf(bestB, a1);
      }
      int s = s0 + g * 4 + w;
      out[24576 + b * 262144 + lane * 512 + s] = bestA + b2A;
      out[24576 + b * 262144 + (lane + 64) * 512 + s] = bestB + b2B;
      __syncthreads();
    }
  } else {
    int scale = blockIdx.y - 1;
    int kk = 8 * (scale + 1);
    float* sW1T = smem;
    float* sb1 = smem + 192;
    float* sfeat = smem + 256;
    float* sh1 = smem + 544;
    const float* W1s = msW1 + scale * 192;
    for (int i = t; i < 192; i += 256) {
      int o = i / 3, c = i - o * 3;
      sW1T[c * 64 + o] = W1s[i];
    }
    if (t < 64) sb1[t] = msb1[scale * 64 + t];
    float wgtA[64], wgtB[64];
#pragma unroll
    for (int j = 0; j < 64; ++j) {
      wgtA[j] = msW2[scale * 8192 + lane * 64 + j];
      wgtB[j] = msW2[scale * 8192 + (lane + 64) * 64 + j];
    }
    float b2A = msb2[scale * 128 + lane], b2B = msb2[scale * 128 + lane + 64];
    __syncthreads();
    int co = 128 * (scale + 1);
    for (int g = 0; g < 2; ++g) {
      if (t < 96) {  // 4 rows x 24 slots (stage all 24; h1 reads only k<kk)
        int rr = t / 24, k = t - rr * 24;
        int s = s0 + g * 4 + rr, row = b * SS + s;
        int id = knn[row * 24 + k];
        float qx, qy, qz;
        if constexpr (USE4) {
          float4 q = xyz4[(b << 13) + id];
          qx = q.x; qy = q.y; qz = q.z;
        } else {
          qx = xyz[b * N3 + id];
          qy = xyz[b * N3 + NN + id];
          qz = xyz[b * N3 + 2 * NN + id];
        }
        float* f = &sfeat[rr * 72 + k * 3];
        f[0] = __fsub_rn(qx, kp[b * 1536 + s]);
        f[1] = __fsub_rn(qy, kp[b * 1536 + SS + s]);
        f[2] = __fsub_rn(qz, kp[b * 1536 + 2 * SS + s]);
      }
      __syncthreads();
      for (int rr = 0; rr < 4; ++rr) {
        for (int u = t; u < kk * 64; u += 256) {
          int k = u >> 6, o = u & 63;
          float acc = sb1[o];
          acc = fmaf(sfeat[rr * 72 + k * 3 + 0], sW1T[o], acc);
          acc = fmaf(sfeat[rr * 72 + k * 3 + 1], sW1T[64 + o], acc);
          acc = fmaf(sfeat[rr * 72 + k * 3 + 2], sW1T[128 + o], acc);
          sh1[rr * 1536 + k * 64 + o] = fmaxf(acc, 0.f);
        }
      }
      __syncthreads();
      float bestA = -1e30f, bestB = -1e30f;
      for (int k = 0; k < kk; ++k) {
        const float4* h4 = (const float4*)&sh1[w * 1536 + k * 64];
        float a0 = 0.f, a1 = 0.f;
#pragma unroll
        for (int j = 0; j < 16; ++j) {
          float4 hv = h4[j];
          a0 = fmaf(hv.x, wgtA[4 * j], a0);
          a0 = fmaf(hv.y, wgtA[4 * j + 1], a0);
          a0 = fmaf(hv.z, wgtA[4 * j + 2], a0);
          a0 = fmaf(hv.w, wgtA[4 * j + 3], a0);
          a1 = fmaf(hv.x, wgtB[4 * j], a1);
          a1 = fmaf(hv.y, wgtB[4 * j + 1], a1);
          a1 = fmaf(hv.z, wgtB[4 * j + 2], a1);
          a1 = fmaf(hv.w, wgtB[4 * j + 3], a1);
        }
        bestA = fmaxf(bestA, a0);
        bestB = fmaxf(bestB, a1);
      }
      int s = s0 + g * 4 + w;
      out[24576 + b * 262144 + (co + lane) * 512 + s] = bestA + b2A;
      out[24576 + b * 262144 + (co + lane + 64) * 512 + s] = bestB + b2B;
      __syncthreads();
    }
  }
}

// ---------------------------------------------------------------------------
extern "C" void kernel_launch(void* const* d_in, const int* in_sizes, int n_in,
                              void* d_out, int out_size, void* d_ws, size_t ws_size,
                              hipStream_t stream) {
  const float* xyz = (const float*)d_in[0];    // l0_xyz  [B,3,N] f32
  const float* pts = (const float*)d_in[1];    // l0_points
  const float* sa_W1 = (const float*)d_in[2];  // [64,6]
  const float* sa_b1 = (const float*)d_in[3];  // [64]
  const float* sa_W2 = (const float*)d_in[4];  // [128,64]
  const float* sa_b2 = (const float*)d_in[5];  // [128]
  const float* ms_W1 = (const float*)d_in[6];  // [3,64,3]
  const float* ms_b1 = (const float*)d_in[7];  // [3,64]
  const float* ms_W2 = (const float*)d_in[8];  // [3,128,64]
  const float* ms_b2 = (const float*)d_in[9];  // [3,128]
  float* out = (float*)d_out;
  const float* kp = (const float*)d_out;  // keypoints written by FPS

  // workspace layout: knn u16[B*S*24] (393216 B) | xyz4 (2 MB) | pts4 (2 MB)
  // | progress u32[16]
  u16* knn = (u16*)d_ws;
  float4* xyz4 = (float4*)((char*)d_ws + 393216);
  float4* pts4 = xyz4 + BB * NN;
  u32* progress = (u32*)(pts4 + BB * NN);
  const size_t need = 393216 + (size_t)2 * BB * NN * sizeof(float4) + 64;
  const bool fused = ws_size >= need;

  if (fused) {
    k_prep<<<BB * NN / 256, 256, 0, stream>>>(xyz, pts, xyz4, pts4, progress);
    k_fps_knn<<<BB + KNN_BLOCKS, 512, 0, stream>>>(xyz, xyz4, out, knn, progress);
    k_mlp<1><<<dim3(BB * 64, 4), 256, 0, stream>>>(xyz, pts, xyz4, pts4, kp, knn,
                                                   sa_W1, sa_b1, sa_W2, sa_b2,
                                                   ms_W1, ms_b1, ms_W2, ms_b2, out);
  } else {
    k_fps_solo<<<BB, 512, 0, stream>>>(xyz, out);
    k_knn_solo<<<(BB * SS) / 4, 256, 0, stream>>>(xyz, kp, knn);
    k_mlp<0><<<dim3(BB * 64, 4), 256, 0, stream>>>(xyz, pts, xyz4, pts4, kp, knn,
                                                   sa_W1, sa_b1, sa_W2, sa_b2,
                                                   ms_W1, ms_b1, ms_W2, ms_b2, out);
  }
}

// Round 7
// 985.512 us; speedup vs baseline: 1.2642x; 1.2642x over previous
//
#include <hip/hip_runtime.h>

#define BB 16
#define NN 8192
#define SS 512
#define N3 (3 * NN)  // 24576 elements per batch per tensor
#define KD 14        // per-lane KNN list depth (see k_knn comment)

typedef unsigned short u16;
typedef unsigned int u32;
typedef unsigned long long u64;
typedef float v2f __attribute__((ext_vector_type(2)));

// Packed fp32 ops (VOP3P, 2 points/inst). Per-half rounding is IEEE rn —
// bit-identical to scalar __fadd_rn/__fmul_rn.
__device__ __forceinline__ v2f pk_add(v2f a, v2f b) {
  v2f r;
  asm("v_pk_add_f32 %0, %1, %2" : "=v"(r) : "v"(a), "v"(b));
  return r;
}
__device__ __forceinline__ v2f pk_mul(v2f a, v2f b) {
  v2f r;
  asm("v_pk_mul_f32 %0, %1, %2" : "=v"(r) : "v"(a), "v"(b));
  return r;
}

// u64 max step over a DPP lane-shift: shift both 32-bit halves with the same
// control (old=0 is the identity for max of our non-negative keys), then one
// v_cmp_lt_u64 + 2 cndmask. Stays entirely on the VALU pipe — r15's lesson:
// __shfl_xor is ds_bpermute (LDS pipe, ~40+cy dependent) and 9 such steps on
// the serial path cost ~+500cy/iter (544 -> 658 us).
template <int CTRL>
__device__ __forceinline__ u64 dpp_maxk(u64 k) {
  u32 lo = (u32)k, hi = (u32)(k >> 32);
  u32 slo = (u32)__builtin_amdgcn_update_dpp(0, (int)lo, CTRL, 0xf, 0xf, false);
  u32 shi = (u32)__builtin_amdgcn_update_dpp(0, (int)hi, CTRL, 0xf, 0xf, false);
  u64 s = ((u64)shi << 32) | (u64)slo;
  return (s > k) ? s : k;
}
// u64 MIN step over a DPP lane-shift (r20, for the KNN merge): identity for
// min is "self" — pass the lane's own value as `old`, so lanes with no DPP
// source (row starts / bcast targets' complement) do min(self,self). Same
// validated control sequence as the max chain (r13/r16 hardware-proven).
template <int CTRL>
__device__ __forceinline__ u64 dpp_mink(u64 k) {
  u32 lo = (u32)k, hi = (u32)(k >> 32);
  u32 slo = (u32)__builtin_amdgcn_update_dpp((int)lo, (int)lo, CTRL, 0xf, 0xf, false);
  u32 shi = (u32)__builtin_amdgcn_update_dpp((int)hi, (int)hi, CTRL, 0xf, 0xf, false);
  u64 s = ((u64)shi << 32) | (u64)slo;
  return (s < k) ? s : k;
}
__device__ __forceinline__ u64 maxk(u64 a, u64 b) { return (a > b) ? a : b; }

// ---------------------------------------------------------------------------
// K0: precompute per-point float4 {x,y,z,|q|^2} for xyz and {x,y,z,0} for
// l0_points into workspace. |q|^2 uses the EXACT rn tree k_knn used in-loop,
// so downstream bits are unchanged.
// r18/r19 post-mortem: both intra-kernel FPS/KNN overlap attempts REGRESSED
// (834/1018us vs serial 506+~300): agent-scope store drains + acquire-poll
// cache invalidations + consumers at 1 block/CU (inherited dead 98KB LDS)
// cost more than the overlap saved. r20 reverts to the serial r17 structure.
// ---------------------------------------------------------------------------
__global__ __launch_bounds__(256) void k_prep(const float* __restrict__ xyz,
                                              const float* __restrict__ pts,
                                              float4* __restrict__ xyz4,
                                              float4* __restrict__ pts4) {
  int i = blockIdx.x * 256 + threadIdx.x;  // < BB*NN
  int b = i >> 13, n = i & (NN - 1);
  const float* xb = xyz + b * N3;
  float x = xb[n], y = xb[NN + n], z = xb[2 * NN + n];
  float w = __fadd_rn(__fadd_rn(__fmul_rn(x, x), __fmul_rn(y, y)), __fmul_rn(z, z));
  xyz4[i] = make_float4(x, y, z, w);
  const float* pb = pts + b * N3;
  pts4[i] = make_float4(pb[n], pb[NN + n], pb[2 * NN + n], 0.f);
}

// ---------------------------------------------------------------------------
// K1: farthest point sampling, fp32, bit-exact vs numpy. r16 structure
// (510us, VALUBusy ~79% of 16-CU cap — near issue-bound at 2 waves/SIMD).
// History: r13 256thr 544us latency-bound; r14 1024thr 661us (4x per-wave
// overhead); r15 512thr+shfl 658us (shfl = ds_bpermute LDS latency);
// r16 512thr, all cross-lane on the VALU pipe: thread-local find vs OWN vmax
// -> ONE u64 DPP max chain -> lane63 ds_write -> ONE barrier -> broadcast
// read of 8 wave keys + redundant VALU tree -> broadcast coords read.
// Exactness: vmax is bit-identical to one of this thread's dm values; d >= +0
// so float bits are order-preserving as u32; key = dist<<32 | (NN-idx): max
// key = max dist, tie -> max (NN-idx) = lowest idx = np.argmax. Within-thread
// ties: descending-j find, last write wins = lowest idx. DPP old=0 is the
// max-identity (keys > 0). Parity double-buffer on rkey.
// ---------------------------------------------------------------------------
__global__ __attribute__((amdgpu_flat_work_group_size(512, 512),
                          amdgpu_waves_per_eu(2, 2)))
void k_fps(const float* __restrict__ xyz, float* __restrict__ out_kp) {
  __shared__ float sxyz[NN * 3];  // [idx][x,y,z]
  __shared__ int sIdx[SS];
  __shared__ u64 rkey[2][8];
  int b = blockIdx.x, t = threadIdx.x;
  const float* base = xyz + b * N3;
  v2f px[8], py[8], pz[8], dm[8];
#pragma unroll
  for (int j = 0; j < 8; ++j) {
    int n0 = j * 1024 + t, n1 = n0 + 512;  // coalesced, disjoint cover [0,8192)
    px[j] = v2f{base[n0], base[n1]};
    py[j] = v2f{base[NN + n0], base[NN + n1]};
    pz[j] = v2f{base[2 * NN + n0], base[2 * NN + n1]};
    dm[j] = v2f{1e10f, 1e10f};
    sxyz[n0 * 3 + 0] = px[j].x;  // stage AoS copy for center re-loads
    sxyz[n0 * 3 + 1] = py[j].x;
    sxyz[n0 * 3 + 2] = pz[j].x;
    sxyz[n1 * 3 + 0] = px[j].y;
    sxyz[n1 * 3 + 1] = py[j].y;
    sxyz[n1 * 3 + 2] = pz[j].y;
  }
#pragma unroll
  for (int j = 0; j < 8; ++j) {
    // Opaque def: blocks rematerialization of the global loads.
    asm volatile("" : "+v"(px[j]), "+v"(py[j]), "+v"(pz[j]));
  }
  // staging writes become visible at iter-0's barrier, before first LDS read
  float cx = base[0], cy = base[NN], cz = base[2 * NN];
  int far = 0;
  int lane = t & 63, w = t >> 6;
  u32 tb = (u32)(NN - t);  // candidate base: cand = NN - gidx (1..8192; 0=none)
  for (int it = 0; it < SS; ++it) {
    if (t == 0) sIdx[it] = far;  // scan emits carry BEFORE update: idx[0]=0
    // negated center, broadcast to both halves (a + (-c) == a - c exactly)
    v2f ncx = v2f{-cx, -cx}, ncy = v2f{-cy, -cy}, ncz = v2f{-cz, -cz};
    float vmax = 0.0f;
#pragma unroll
    for (int j = 0; j < 8; ++j) {
      v2f dx = pk_add(px[j], ncx);
      v2f dy = pk_add(py[j], ncy);
      v2f dz = pk_add(pz[j], ncz);
      v2f xx = pk_mul(dx, dx);
      v2f yy = pk_mul(dy, dy);
      v2f s = pk_add(xx, yy);
      v2f zz = pk_mul(dz, dz);
      v2f d = pk_add(s, zz);  // ((dx^2+dy^2)+dz^2), numpy tree per half
      float a0 = fminf(dm[j].x, d.x);
      float a1 = fminf(dm[j].y, d.y);
      dm[j].x = a0;
      dm[j].y = a1;
      vmax = fmaxf(vmax, fmaxf(a0, a1));  // max3-foldable
    }
    // thread-local find vs this thread's OWN max: exact bit-equality (vmax IS
    // one of this thread's dm values). Descending gidx order -> LAST write =
    // lowest gidx within the thread.
    u32 cand = 0;
#pragma unroll
    for (int j = 7; j >= 0; --j) {
      u32 v1 = tb - (u32)(j * 1024 + 512);  // cand for .y half (higher gidx)
      u32 v0 = tb - (u32)(j * 1024);        // cand for .x half
      cand = (dm[j].y == vmax) ? v1 : cand;
      cand = (dm[j].x == vmax) ? v0 : cand;
    }
    // one packed key per thread; 6-step DPP u64 max chain -> lane63 holds the
    // wave best (max dist, tie -> max cand = min gidx). VALU pipe only.
    u64 key = ((u64)__float_as_uint(vmax) << 32) | cand;
    key = dpp_maxk<0x111>(key);  // row_shr:1
    key = dpp_maxk<0x112>(key);  // row_shr:2
    key = dpp_maxk<0x114>(key);  // row_shr:4
    key = dpp_maxk<0x118>(key);  // row_shr:8
    key = dpp_maxk<0x142>(key);  // row_bcast:15
    key = dpp_maxk<0x143>(key);  // row_bcast:31 -> lane63 = wave max
    int pb = it & 1;  // parity double-buffer: safe with one barrier/iter
    if (lane == 63) rkey[pb][w] = key;
    __syncthreads();  // the only barrier per iteration
    // block reduce over 8 wave keys: every thread broadcast-reads all 8 slots
    // (one pipelined LDS round trip, all-lane-same-addr) + redundant VALU
    // tree. No cross-lane ops at all in this phase.
    u64 k0 = rkey[pb][0], k1 = rkey[pb][1];
    u64 k2 = rkey[pb][2], k3 = rkey[pb][3];
    u64 k4 = rkey[pb][4], k5 = rkey[pb][5];
    u64 k6 = rkey[pb][6], k7 = rkey[pb][7];
    u64 kg = maxk(maxk(maxk(k0, k1), maxk(k2, k3)),
                  maxk(maxk(k4, k5), maxk(k6, k7)));
    far = NN - (int)(u32)(kg & 0xffffffffu);
    // broadcast ds_read of the winner's coords (all lanes same address,
    // 3 consecutive dwords)
    cx = sxyz[far * 3 + 0];
    cy = sxyz[far * 3 + 1];
    cz = sxyz[far * 3 + 2];
  }
  __syncthreads();
  for (int i = t; i < SS; i += 512) {
    int id = sIdx[i];
    out_kp[b * 1536 + i] = base[id];  // exact fp32 copies
    out_kp[b * 1536 + SS + i] = base[NN + id];
    out_kp[b * 1536 + 2 * SS + i] = base[2 * NN + id];
  }
}

// ---------------------------------------------------------------------------
// K2: per (b,s) row, sorted top-24 nearest (dist asc, idx asc) — prefixes give
// K=8/16/24 and base K=16 (lax.top_k stable tie-break). One wave per row.
// KD=14 per-lane depth (r11 win): top-24 indices ~uniform mod 64, P(any lane
// holds >=15 of 24) < 1e-15 over all rows.
// r17: USE4 path loads ONE float4 {x,y,z,|q|^2} per chunk; insertion uses
// explicitly CSE'd conditions.
// r20: merge wave-min moved from __shfl_xor butterflies (= ds_bpermute, LDS
// pipe: 24 iters x 6 DEPENDENT steps ~ 5-8k cy/row of unhidden latency — the
// r15 lesson) to a 6-step DPP u64 MIN chain on the VALU pipe + 2 readlane
// (SALU broadcast). Exact same min over the same 64 unique keys -> identical
// winner sequence -> bit-identical output.
// d = (|a|^2+|q|^2) - 2*dot, all rn ops, matching the numpy expression tree;
// prep's |q|^2 uses the identical tree -> bit-identical d.
// ---------------------------------------------------------------------------
template <int USE4>
__global__ __launch_bounds__(256) void k_knn(const float* __restrict__ xyz,
                                             const float4* __restrict__ xyz4,
                                             const float* __restrict__ kp,
                                             u16* __restrict__ knn) {
  int t = threadIdx.x;
  int row = blockIdx.x * 4 + (t >> 6);
  int lane = t & 63;
  int b = row >> 9, s = row & (SS - 1);
  const float* base = xyz + b * N3;
  const float4* base4 = xyz4 + (b << 13);
  float ax = kp[b * 1536 + s];
  float ay = kp[b * 1536 + SS + s];
  float az = kp[b * 1536 + 2 * SS + s];
  float aw = __fadd_rn(__fadd_rn(__fmul_rn(ax, ax), __fmul_rn(ay, ay)), __fmul_rn(az, az));
  u64 arr[KD];
#pragma unroll
  for (int i = 0; i < KD; ++i) arr[i] = ~0ull;
  for (int c = 0; c < 128; ++c) {
    int n = c * 64 + lane;
    float qx, qy, qz, qw;
    if constexpr (USE4) {
      float4 q = base4[n];  // one dwordx4, coalesced
      qx = q.x; qy = q.y; qz = q.z; qw = q.w;
    } else {
      qx = base[n]; qy = base[NN + n]; qz = base[2 * NN + n];
      qw = __fadd_rn(__fadd_rn(__fmul_rn(qx, qx), __fmul_rn(qy, qy)), __fmul_rn(qz, qz));
    }
    float dot = __fadd_rn(__fadd_rn(__fmul_rn(ax, qx), __fmul_rn(ay, qy)), __fmul_rn(az, qz));
    float d = __fsub_rn(__fadd_rn(aw, qw), __fmul_rn(2.0f, dot));
    u32 ub = __float_as_uint(d);
    ub ^= (ub & 0x80000000u) ? 0xFFFFFFFFu : 0x80000000u;  // order-preserving map
    u64 key = ((u64)ub << 32) | (u32)n;
    if (key < arr[KD - 1]) {  // sorted insert, conditions CSE'd explicitly
      bool cg[KD];
#pragma unroll
      for (int i = 0; i < KD; ++i) cg[i] = arr[i] > key;
#pragma unroll
      for (int i = KD - 1; i >= 1; --i)
        arr[i] = cg[i - 1] ? arr[i - 1] : (cg[i] ? key : arr[i]);
      arr[0] = cg[0] ? key : arr[0];
    }
  }
  // merge 64 sorted lists: 24 x (wave-min of heads via DPP chain (VALU pipe)
  // + readlane broadcast; winner pops). keys unique -> exactly one popper.
  u64 mine = 0;
  for (int it = 0; it < 24; ++it) {
    u64 m = arr[0];
    m = dpp_mink<0x111>(m);  // row_shr:1
    m = dpp_mink<0x112>(m);  // row_shr:2
    m = dpp_mink<0x114>(m);  // row_shr:4
    m = dpp_mink<0x118>(m);  // row_shr:8
    m = dpp_mink<0x142>(m);  // row_bcast:15
    m = dpp_mink<0x143>(m);  // row_bcast:31 -> lane63 = wave min
    u32 mlo = (u32)__builtin_amdgcn_readlane((int)(u32)m, 63);
    u32 mhi = (u32)__builtin_amdgcn_readlane((int)(u32)(m >> 32), 63);
    u64 mw = ((u64)mhi << 32) | (u64)mlo;  // wave-uniform (SGPR) min
    if (lane == it) mine = mw;
    if (arr[0] == mw) {  // per-lane predicate; <=1 lane true
#pragma unroll
      for (int i = 0; i < KD - 1; ++i) arr[i] = arr[i + 1];
      arr[KD - 1] = ~0ull;
    }
  }
  if (lane < 24) knn[row * 24 + lane] = (u16)(mine & 0xFFFFu);
}

// ---------------------------------------------------------------------------
// K3 (r17, unchanged): fused base-SA + multi-scale MLPs. blockIdx.y = 0 ->
// base (feat [rel_xyz|pts] 6->64 relu -> 64->128, K=16, out ch 0..127);
// blockIdx.y = 1..3 -> ms scale y-1 (rel_xyz 3->64 relu -> 64->128, K=8y,
// out ch 128y..128y+127). Branch is block-uniform. Staging gathers via
// float4 (USE4). Per-wave h2: thread owns 2 out channels, W2 rows in
// registers, h1 read as wave-uniform float4 broadcast.
// ---------------------------------------------------------------------------
template <int USE4>
__global__ __launch_bounds__(256) void k_mlp(
    const float* __restrict__ xyz, const float* __restrict__ pts,
    const float4* __restrict__ xyz4, const float4* __restrict__ pts4,
    const float* __restrict__ kp, const u16* __restrict__ knn,
    const float* __restrict__ W1, const float* __restrict__ b1,
    const float* __restrict__ W2, const float* __restrict__ b2,
    const float* __restrict__ msW1, const float* __restrict__ msb1,
    const float* __restrict__ msW2, const float* __restrict__ msb2,
    float* __restrict__ out) {
  __shared__ float smem[6688];
  int t = threadIdx.x, lane = t & 63, w = t >> 6;
  int b = blockIdx.x >> 6, s0 = (blockIdx.x & 63) * 8;
  if (blockIdx.y == 0) {
    float* sW1T = smem;          // [c][o] 6*64
    float* sb1 = smem + 384;     // 64
    float* sfeat = smem + 448;   // [row][k*6+c] 4*96
    float* sh1 = smem + 832;     // [row][k*64+o] 4*1024
    for (int i = t; i < 384; i += 256) {
      int o = i / 6, c = i - o * 6;
      sW1T[c * 64 + o] = W1[i];
    }
    if (t < 64) sb1[t] = b1[t];
    float wgtA[64], wgtB[64];
#pragma unroll
    for (int j = 0; j < 64; ++j) {
      wgtA[j] = W2[lane * 64 + j];
      wgtB[j] = W2[(lane + 64) * 64 + j];
    }
    float b2A = b2[lane], b2B = b2[lane + 64];
    __syncthreads();
    for (int g = 0; g < 2; ++g) {
      if (t < 128) {  // 64 (rr,k) pairs x 2 halves: h=0 xyz, h=1 pts
        int p = t >> 1, h = t & 1;
        int rr = p >> 4, k = p & 15;
        int s = s0 + g * 4 + rr, row = b * SS + s;
        int id = knn[row * 24 + k];  // first 16 of sorted top-24 = base KNN
        float* f = &sfeat[rr * 96 + k * 6];
        if (h == 0) {
          float qx, qy, qz;
          if constexpr (USE4) {
            float4 q = xyz4[(b << 13) + id];
            qx = q.x; qy = q.y; qz = q.z;
          } else {
            qx = xyz[b * N3 + id];
            qy = xyz[b * N3 + NN + id];
            qz = xyz[b * N3 + 2 * NN + id];
          }
          f[0] = __fsub_rn(qx, kp[b * 1536 + s]);
          f[1] = __fsub_rn(qy, kp[b * 1536 + SS + s]);
          f[2] = __fsub_rn(qz, kp[b * 1536 + 2 * SS + s]);
        } else {
          float px_, py_, pz_;
          if constexpr (USE4) {
            float4 q = pts4[(b << 13) + id];
            px_ = q.x; py_ = q.y; pz_ = q.z;
          } else {
            px_ = pts[b * N3 + id];
            py_ = pts[b * N3 + NN + id];
            pz_ = pts[b * N3 + 2 * NN + id];
          }
          f[3] = px_;
          f[4] = py_;
          f[5] = pz_;
        }
      }
      __syncthreads();
#pragma unroll
      for (int m = 0; m < 16; ++m) {  // 4 rows x 1024 h1 entries / 256 thr
        int u = m * 256 + t;
        int rr = u >> 10, rem = u & 1023, k = rem >> 6, o = rem & 63;
        float acc = sb1[o];
#pragma unroll
        for (int c = 0; c < 6; ++c) acc = fmaf(sfeat[rr * 96 + k * 6 + c], sW1T[c * 64 + o], acc);
        sh1[rr * 1024 + k * 64 + o] = fmaxf(acc, 0.f);
      }
      __syncthreads();
      float bestA = -1e30f, bestB = -1e30f;
#pragma unroll
      for (int k = 0; k < 16; ++k) {
        const float4* h4 = (const float4*)&sh1[w * 1024 + k * 64];  // wave-uniform bcast
        float a0 = 0.f, a1 = 0.f;
#pragma unroll
        for (int j = 0; j < 16; ++j) {
          float4 hv = h4[j];
          a0 = fmaf(hv.x, wgtA[4 * j], a0);
          a0 = fmaf(hv.y, wgtA[4 * j + 1], a0);
          a0 = fmaf(hv.z, wgtA[4 * j + 2], a0);
          a0 = fmaf(hv.w, wgtA[4 * j + 3], a0);
          a1 = fmaf(hv.x, wgtB[4 * j], a1);
          a1 = fmaf(hv.y, wgtB[4 * j + 1], a1);
          a1 = fmaf(hv.z, wgtB[4 * j + 2], a1);
          a1 = fmaf(hv.w, wgtB[4 * j + 3], a1);
        }
        bestA = fmaxf(bestA, a0);
        bestB = fmaxf(bestB, a1);
      }
      int s = s0 + g * 4 + w;
      out[24576 + b * 262144 + lane * 512 + s] = bestA + b2A;
      out[24576 + b * 262144 + (lane + 64) * 512 + s] = bestB + b2B;
      __syncthreads();  // protect sfeat/sh1 before next group overwrites
    }
  } else {
    int scale = blockIdx.y - 1;
    int kk = 8 * (scale + 1);
    float* sW1T = smem;          // [c][o] 3*64
    float* sb1 = smem + 192;     // 64
    float* sfeat = smem + 256;   // [row][k*3+c] 4*72
    float* sh1 = smem + 544;     // [row][k*64+o] 4*1536
    const float* W1s = msW1 + scale * 192;
    for (int i = t; i < 192; i += 256) {
      int o = i / 3, c = i - o * 3;
      sW1T[c * 64 + o] = W1s[i];
    }
    if (t < 64) sb1[t] = msb1[scale * 64 + t];
    float wgtA[64], wgtB[64];
#pragma unroll
    for (int j = 0; j < 64; ++j) {
      wgtA[j] = msW2[scale * 8192 + lane * 64 + j];
      wgtB[j] = msW2[scale * 8192 + (lane + 64) * 64 + j];
    }
    float b2A = msb2[scale * 128 + lane], b2B = msb2[scale * 128 + lane + 64];
    __syncthreads();
    int co = 128 * (scale + 1);
    for (int g = 0; g < 2; ++g) {
      if (t < 96) {  // 4 rows x 24 slots (stage all 24; h1 reads only k<kk)
        int rr = t / 24, k = t - rr * 24;  // constant divisor -> mul-shift
        int s = s0 + g * 4 + rr, row = b * SS + s;
        int id = knn[row * 24 + k];
        float qx, qy, qz;
        if constexpr (USE4) {
          float4 q = xyz4[(b << 13) + id];
          qx = q.x; qy = q.y; qz = q.z;
        } else {
          qx = xyz[b * N3 + id];
          qy = xyz[b * N3 + NN + id];
          qz = xyz[b * N3 + 2 * NN + id];
        }
        float* f = &sfeat[rr * 72 + k * 3];
        f[0] = __fsub_rn(qx, kp[b * 1536 + s]);
        f[1] = __fsub_rn(qy, kp[b * 1536 + SS + s]);
        f[2] = __fsub_rn(qz, kp[b * 1536 + 2 * SS + s]);
      }
      __syncthreads();
      for (int rr = 0; rr < 4; ++rr) {  // h1 for kk*64 entries per row
        for (int u = t; u < kk * 64; u += 256) {
          int k = u >> 6, o = u & 63;
          float acc = sb1[o];
          acc = fmaf(sfeat[rr * 72 + k * 3 + 0], sW1T[o], acc);
          acc = fmaf(sfeat[rr * 72 + k * 3 + 1], sW1T[64 + o], acc);
          acc = fmaf(sfeat[rr * 72 + k * 3 + 2], sW1T[128 + o], acc);
          sh1[rr * 1536 + k * 64 + o] = fmaxf(acc, 0.f);
        }
      }
      __syncthreads();
      float bestA = -1e30f, bestB = -1e30f;
      for (int k = 0; k < kk; ++k) {  // kk uniform across block -> no divergence
        const float4* h4 = (const float4*)&sh1[w * 1536 + k * 64];
        float a0 = 0.f, a1 = 0.f;
#pragma unroll
        for (int j = 0; j < 16; ++j) {
          float4 hv = h4[j];
          a0 = fmaf(hv.x, wgtA[4 * j], a0);
          a0 = fmaf(hv.y, wgtA[4 * j + 1], a0);
          a0 = fmaf(hv.z, wgtA[4 * j + 2], a0);
          a0 = fmaf(hv.w, wgtA[4 * j + 3], a0);
          a1 = fmaf(hv.x, wgtB[4 * j], a1);
          a1 = fmaf(hv.y, wgtB[4 * j + 1], a1);
          a1 = fmaf(hv.z, wgtB[4 * j + 2], a1);
          a1 = fmaf(hv.w, wgtB[4 * j + 3], a1);
        }
        bestA = fmaxf(bestA, a0);
        bestB = fmaxf(bestB, a1);
      }
      int s = s0 + g * 4 + w;
      out[24576 + b * 262144 + (co + lane) * 512 + s] = bestA + b2A;
      out[24576 + b * 262144 + (co + lane + 64) * 512 + s] = bestB + b2B;
      __syncthreads();
    }
  }
}

// ---------------------------------------------------------------------------
extern "C" void kernel_launch(void* const* d_in, const int* in_sizes, int n_in,
                              void* d_out, int out_size, void* d_ws, size_t ws_size,
                              hipStream_t stream) {
  const float* xyz = (const float*)d_in[0];    // l0_xyz  [B,3,N] f32
  const float* pts = (const float*)d_in[1];    // l0_points
  const float* sa_W1 = (const float*)d_in[2];  // [64,6]
  const float* sa_b1 = (const float*)d_in[3];  // [64]
  const float* sa_W2 = (const float*)d_in[4];  // [128,64]
  const float* sa_b2 = (const float*)d_in[5];  // [128]
  const float* ms_W1 = (const float*)d_in[6];  // [3,64,3]
  const float* ms_b1 = (const float*)d_in[7];  // [3,64]
  const float* ms_W2 = (const float*)d_in[8];  // [3,128,64]
  const float* ms_b2 = (const float*)d_in[9];  // [3,128]
  float* out = (float*)d_out;
  const float* kp = (const float*)d_out;  // keypoints written by k_fps

  // workspace: knn u16[B*S*24] = 393216 B, then xyz4/pts4 float4[B*N] = 2 MB each
  u16* knn = (u16*)d_ws;
  float4* xyz4 = (float4*)((char*)d_ws + 393216);
  float4* pts4 = xyz4 + BB * NN;
  const size_t need4 = 393216 + (size_t)2 * BB * NN * sizeof(float4);
  const bool use4 = ws_size >= need4;

  if (use4) k_prep<<<BB * NN / 256, 256, 0, stream>>>(xyz, pts, xyz4, pts4);
  k_fps<<<BB, 512, 0, stream>>>(xyz, out);
  if (use4) {
    k_knn<1><<<(BB * SS) / 4, 256, 0, stream>>>(xyz, xyz4, kp, knn);
    k_mlp<1><<<dim3(BB * 64, 4), 256, 0, stream>>>(xyz, pts, xyz4, pts4, kp, knn,
                                                   sa_W1, sa_b1, sa_W2, sa_b2,
                                                   ms_W1, ms_b1, ms_W2, ms_b2, out);
  } else {
    k_knn<0><<<(BB * SS) / 4, 256, 0, stream>>>(xyz, xyz4, kp, knn);
    k_mlp<0><<<dim3(BB * 64, 4), 256, 0, stream>>>(xyz, pts, xyz4, pts4, kp, knn,
                                                   sa_W1, sa_b1, sa_W2, sa_b2,
                                                   ms_W1, ms_b1, ms_W2, ms_b2, out);
  }
}

// Round 8
// 904.279 us; speedup vs baseline: 1.3778x; 1.0898x over previous
//
#include <hip/hip_runtime.h>

#define BB 16
#define NN 8192
#define SS 512
#define N3 (3 * NN)  // 24576 elements per batch per tensor
#define KD 14        // per-lane depth for the SOLO (1-wave-per-row) fallback
#define KDB 7        // per-lane depth for the block-per-row kernel (32 pts/lane)

typedef unsigned short u16;
typedef unsigned int u32;
typedef unsigned long long u64;
typedef float v2f __attribute__((ext_vector_type(2)));

// Packed fp32 ops (VOP3P, 2 points/inst). Per-half rounding is IEEE rn —
// bit-identical to scalar __fadd_rn/__fmul_rn.
__device__ __forceinline__ v2f pk_add(v2f a, v2f b) {
  v2f r;
  asm("v_pk_add_f32 %0, %1, %2" : "=v"(r) : "v"(a), "v"(b));
  return r;
}
__device__ __forceinline__ v2f pk_mul(v2f a, v2f b) {
  v2f r;
  asm("v_pk_mul_f32 %0, %1, %2" : "=v"(r) : "v"(a), "v"(b));
  return r;
}

// u64 max step over a DPP lane-shift (FPS): old=0 is the max identity for our
// positive keys.
template <int CTRL>
__device__ __forceinline__ u64 dpp_maxk(u64 k) {
  u32 lo = (u32)k, hi = (u32)(k >> 32);
  u32 slo = (u32)__builtin_amdgcn_update_dpp(0, (int)lo, CTRL, 0xf, 0xf, false);
  u32 shi = (u32)__builtin_amdgcn_update_dpp(0, (int)hi, CTRL, 0xf, 0xf, false);
  u64 s = ((u64)shi << 32) | (u64)slo;
  return (s > k) ? s : k;
}
// u64 MIN step over a DPP lane-shift (KNN merges): old=self is the min
// identity. r20 note: vs __shfl_xor this is latency-equivalent-or-better and
// was neutral at high occupancy — kept because it's in place and correct.
template <int CTRL>
__device__ __forceinline__ u64 dpp_mink(u64 k) {
  u32 lo = (u32)k, hi = (u32)(k >> 32);
  u32 slo = (u32)__builtin_amdgcn_update_dpp((int)lo, (int)lo, CTRL, 0xf, 0xf, false);
  u32 shi = (u32)__builtin_amdgcn_update_dpp((int)hi, (int)hi, CTRL, 0xf, 0xf, false);
  u64 s = ((u64)shi << 32) | (u64)slo;
  return (s < k) ? s : k;
}
__device__ __forceinline__ u64 maxk(u64 a, u64 b) { return (a > b) ? a : b; }

// wave-min of `m` to ALL-lanes-usable form: 6-step DPP chain -> lane63, then
// 2 readlanes -> SGPR-uniform u64.
__device__ __forceinline__ u64 wave_min_u64(u64 m) {
  m = dpp_mink<0x111>(m);  // row_shr:1
  m = dpp_mink<0x112>(m);  // row_shr:2
  m = dpp_mink<0x114>(m);  // row_shr:4
  m = dpp_mink<0x118>(m);  // row_shr:8
  m = dpp_mink<0x142>(m);  // row_bcast:15
  m = dpp_mink<0x143>(m);  // row_bcast:31 -> lane63 = wave min
  u32 mlo = (u32)__builtin_amdgcn_readlane((int)(u32)m, 63);
  u32 mhi = (u32)__builtin_amdgcn_readlane((int)(u32)(m >> 32), 63);
  return ((u64)mhi << 32) | (u64)mlo;
}

// ---------------------------------------------------------------------------
// K0: precompute per-point float4 {x,y,z,|q|^2} for xyz and {x,y,z,0} for
// l0_points into workspace. |q|^2 uses the EXACT rn tree -> bits unchanged
// downstream.
// ---------------------------------------------------------------------------
__global__ __launch_bounds__(256) void k_prep(const float* __restrict__ xyz,
                                              const float* __restrict__ pts,
                                              float4* __restrict__ xyz4,
                                              float4* __restrict__ pts4) {
  int i = blockIdx.x * 256 + threadIdx.x;  // < BB*NN
  int b = i >> 13, n = i & (NN - 1);
  const float* xb = xyz + b * N3;
  float x = xb[n], y = xb[NN + n], z = xb[2 * NN + n];
  float w = __fadd_rn(__fadd_rn(__fmul_rn(x, x), __fmul_rn(y, y)), __fmul_rn(z, z));
  xyz4[i] = make_float4(x, y, z, w);
  const float* pb = pts + b * N3;
  pts4[i] = make_float4(pb[n], pb[NN + n], pb[2 * NN + n], 0.f);
}

// ---------------------------------------------------------------------------
// K1: farthest point sampling, fp32, bit-exact vs numpy. r16 structure,
// UNCHANGED (508us, ~79% of the 16-CU issue cap; 16 blocks pinned to 16 CUs
// is the structural limit — overlap attempts r18/r19 both regressed on
// agent-scope store drains + acquire-poll invalidation traffic).
// ---------------------------------------------------------------------------
__global__ __attribute__((amdgpu_flat_work_group_size(512, 512),
                          amdgpu_waves_per_eu(2, 2)))
void k_fps(const float* __restrict__ xyz, float* __restrict__ out_kp) {
  __shared__ float sxyz[NN * 3];  // [idx][x,y,z]
  __shared__ int sIdx[SS];
  __shared__ u64 rkey[2][8];
  int b = blockIdx.x, t = threadIdx.x;
  const float* base = xyz + b * N3;
  v2f px[8], py[8], pz[8], dm[8];
#pragma unroll
  for (int j = 0; j < 8; ++j) {
    int n0 = j * 1024 + t, n1 = n0 + 512;  // coalesced, disjoint cover [0,8192)
    px[j] = v2f{base[n0], base[n1]};
    py[j] = v2f{base[NN + n0], base[NN + n1]};
    pz[j] = v2f{base[2 * NN + n0], base[2 * NN + n1]};
    dm[j] = v2f{1e10f, 1e10f};
    sxyz[n0 * 3 + 0] = px[j].x;  // stage AoS copy for center re-loads
    sxyz[n0 * 3 + 1] = py[j].x;
    sxyz[n0 * 3 + 2] = pz[j].x;
    sxyz[n1 * 3 + 0] = px[j].y;
    sxyz[n1 * 3 + 1] = py[j].y;
    sxyz[n1 * 3 + 2] = pz[j].y;
  }
#pragma unroll
  for (int j = 0; j < 8; ++j) {
    // Opaque def: blocks rematerialization of the global loads.
    asm volatile("" : "+v"(px[j]), "+v"(py[j]), "+v"(pz[j]));
  }
  // staging writes become visible at iter-0's barrier, before first LDS read
  float cx = base[0], cy = base[NN], cz = base[2 * NN];
  int far = 0;
  int lane = t & 63, w = t >> 6;
  u32 tb = (u32)(NN - t);  // candidate base: cand = NN - gidx (1..8192; 0=none)
  for (int it = 0; it < SS; ++it) {
    if (t == 0) sIdx[it] = far;  // scan emits carry BEFORE update: idx[0]=0
    // negated center, broadcast to both halves (a + (-c) == a - c exactly)
    v2f ncx = v2f{-cx, -cx}, ncy = v2f{-cy, -cy}, ncz = v2f{-cz, -cz};
    float vmax = 0.0f;
#pragma unroll
    for (int j = 0; j < 8; ++j) {
      v2f dx = pk_add(px[j], ncx);
      v2f dy = pk_add(py[j], ncy);
      v2f dz = pk_add(pz[j], ncz);
      v2f xx = pk_mul(dx, dx);
      v2f yy = pk_mul(dy, dy);
      v2f s = pk_add(xx, yy);
      v2f zz = pk_mul(dz, dz);
      v2f d = pk_add(s, zz);  // ((dx^2+dy^2)+dz^2), numpy tree per half
      float a0 = fminf(dm[j].x, d.x);
      float a1 = fminf(dm[j].y, d.y);
      dm[j].x = a0;
      dm[j].y = a1;
      vmax = fmaxf(vmax, fmaxf(a0, a1));  // max3-foldable
    }
    // thread-local find vs this thread's OWN max: exact bit-equality (vmax IS
    // one of this thread's dm values). Descending gidx order -> LAST write =
    // lowest gidx within the thread.
    u32 cand = 0;
#pragma unroll
    for (int j = 7; j >= 0; --j) {
      u32 v1 = tb - (u32)(j * 1024 + 512);  // cand for .y half (higher gidx)
      u32 v0 = tb - (u32)(j * 1024);        // cand for .x half
      cand = (dm[j].y == vmax) ? v1 : cand;
      cand = (dm[j].x == vmax) ? v0 : cand;
    }
    // one packed key per thread; 6-step DPP u64 max chain -> lane63 holds the
    // wave best (max dist, tie -> max cand = min gidx). VALU pipe only.
    u64 key = ((u64)__float_as_uint(vmax) << 32) | cand;
    key = dpp_maxk<0x111>(key);  // row_shr:1
    key = dpp_maxk<0x112>(key);  // row_shr:2
    key = dpp_maxk<0x114>(key);  // row_shr:4
    key = dpp_maxk<0x118>(key);  // row_shr:8
    key = dpp_maxk<0x142>(key);  // row_bcast:15
    key = dpp_maxk<0x143>(key);  // row_bcast:31 -> lane63 = wave max
    int pb = it & 1;  // parity double-buffer: safe with one barrier/iter
    if (lane == 63) rkey[pb][w] = key;
    __syncthreads();  // the only barrier per iteration
    // block reduce over 8 wave keys: every thread broadcast-reads all 8 slots
    // + redundant VALU tree. No cross-lane ops at all in this phase.
    u64 k0 = rkey[pb][0], k1 = rkey[pb][1];
    u64 k2 = rkey[pb][2], k3 = rkey[pb][3];
    u64 k4 = rkey[pb][4], k5 = rkey[pb][5];
    u64 k6 = rkey[pb][6], k7 = rkey[pb][7];
    u64 kg = maxk(maxk(maxk(k0, k1), maxk(k2, k3)),
                  maxk(maxk(k4, k5), maxk(k6, k7)));
    far = NN - (int)(u32)(kg & 0xffffffffu);
    // broadcast ds_read of the winner's coords (all lanes same address)
    cx = sxyz[far * 3 + 0];
    cy = sxyz[far * 3 + 1];
    cz = sxyz[far * 3 + 2];
  }
  __syncthreads();
  for (int i = t; i < SS; i += 512) {
    int id = sIdx[i];
    out_kp[b * 1536 + i] = base[id];  // exact fp32 copies
    out_kp[b * 1536 + SS + i] = base[NN + id];
    out_kp[b * 1536 + 2 * SS + i] = base[2 * NN + id];
  }
}

// ---------------------------------------------------------------------------
// K2 (r21): one ROW per 256-thread BLOCK (was: per wave). Motivation: the
// sorted-insert body runs at ~every chunk (P(any-lane inserts) ~ 1), costing
// ~KD*4 insts/chunk; its total scales with points-per-lane (chunks) AND list
// depth KD. Block-per-row: 32 pts/lane (was 128) and KDB=7 (was 14) —
// failure needs a lane holding >= 8 of the global top-24 (p=1/256 per key:
// P ~ 4e-14/lane, ~8e-8 per full run). Insert issue per row drops ~4-5x.
// Merge is 3-level, each level an EXACT min-extract over unique keys ->
// output bit-identical to the 1-wave version:
//   A: per-wave 24-extract (DPP-min + pop), wave's sorted 24 -> LDS
//   B: wave 0 merges 4x24: lane l holds {sk[l], l<32 ? sk[64+l] : ~0} as a
//      sorted 2-list; 24x (wave-min + pop). keys unique -> exact.
// d = (|a|^2+|q|^2) - 2*dot, all rn, |q|^2 from prep (identical tree).
// ---------------------------------------------------------------------------
__global__ __launch_bounds__(256) void k_knn_blk(const float4* __restrict__ xyz4,
                                                 const float* __restrict__ kp,
                                                 u16* __restrict__ knn) {
  __shared__ u64 skeys[96];
  int t = threadIdx.x, lane = t & 63, w = t >> 6;
  int b = blockIdx.x >> 9, s = blockIdx.x & (SS - 1);
  const float4* base4 = xyz4 + (b << 13);
  float ax = kp[b * 1536 + s];
  float ay = kp[b * 1536 + SS + s];
  float az = kp[b * 1536 + 2 * SS + s];
  float aw = __fadd_rn(__fadd_rn(__fmul_rn(ax, ax), __fmul_rn(ay, ay)), __fmul_rn(az, az));
  u64 arr[KDB];
#pragma unroll
  for (int i = 0; i < KDB; ++i) arr[i] = ~0ull;
  for (int c = 0; c < 32; ++c) {
    int n = c * 256 + t;  // coalesced across the block, disjoint cover
    float4 q = base4[n];  // one dwordx4
    float dot = __fadd_rn(__fadd_rn(__fmul_rn(ax, q.x), __fmul_rn(ay, q.y)),
                          __fmul_rn(az, q.z));
    float d = __fsub_rn(__fadd_rn(aw, q.w), __fmul_rn(2.0f, dot));
    u32 ub = __float_as_uint(d);
    ub ^= (ub & 0x80000000u) ? 0xFFFFFFFFu : 0x80000000u;  // order-preserving map
    u64 key = ((u64)ub << 32) | (u32)n;
    if (key < arr[KDB - 1]) {  // sorted insert, CSE'd conditions
      bool cg[KDB];
#pragma unroll
      for (int i = 0; i < KDB; ++i) cg[i] = arr[i] > key;
#pragma unroll
      for (int i = KDB - 1; i >= 1; --i)
        arr[i] = cg[i - 1] ? arr[i - 1] : (cg[i] ? key : arr[i]);
      arr[0] = cg[0] ? key : arr[0];
    }
  }
  // phase A: per-wave merge of 64 sorted lists -> wave's sorted top-24
  u64 mine = 0;
  for (int it = 0; it < 24; ++it) {
    u64 mw = wave_min_u64(arr[0]);
    if (lane == it) mine = mw;
    if (arr[0] == mw) {  // unique keys -> exactly one popper
#pragma unroll
      for (int i = 0; i < KDB - 1; ++i) arr[i] = arr[i + 1];
      arr[KDB - 1] = ~0ull;
    }
  }
  if (lane < 24) skeys[w * 24 + lane] = mine;
  __syncthreads();
  // phase B: wave 0 merges the 4 sorted 24-lists (96 unique keys)
  if (w == 0) {
    u64 a = skeys[lane];
    u64 b2 = (lane < 32) ? skeys[64 + lane] : ~0ull;
    u64 lo = (a < b2) ? a : b2;
    u64 hi = (a < b2) ? b2 : a;
    u64 outk = 0;
    for (int it = 0; it < 24; ++it) {
      u64 mw = wave_min_u64(lo);
      if (lane == it) outk = mw;
      if (lo == mw) {
        lo = hi;
        hi = ~0ull;
      }
    }
    if (lane < 24) knn[blockIdx.x * 24 + lane] = (u16)(outk & 0xFFFFu);
  }
}

// ---------------------------------------------------------------------------
// Fallback solo KNN (workspace too small for float4): r17 scalar path,
// 1 wave per row, KD=14.
// ---------------------------------------------------------------------------
__global__ __launch_bounds__(256) void k_knn_solo(const float* __restrict__ xyz,
                                                  const float* __restrict__ kp,
                                                  u16* __restrict__ knn) {
  int t = threadIdx.x;
  int row = blockIdx.x * 4 + (t >> 6);
  int lane = t & 63;
  int b = row >> 9, s = row & (SS - 1);
  const float* base = xyz + b * N3;
  float ax = kp[b * 1536 + s];
  float ay = kp[b * 1536 + SS + s];
  float az = kp[b * 1536 + 2 * SS + s];
  float aw = __fadd_rn(__fadd_rn(__fmul_rn(ax, ax), __fmul_rn(ay, ay)), __fmul_rn(az, az));
  u64 arr[KD];
#pragma unroll
  for (int i = 0; i < KD; ++i) arr[i] = ~0ull;
  for (int c = 0; c < 128; ++c) {
    int n = c * 64 + lane;
    float qx = base[n], qy = base[NN + n], qz = base[2 * NN + n];
    float qw = __fadd_rn(__fadd_rn(__fmul_rn(qx, qx), __fmul_rn(qy, qy)), __fmul_rn(qz, qz));
    float dot = __fadd_rn(__fadd_rn(__fmul_rn(ax, qx), __fmul_rn(ay, qy)), __fmul_rn(az, qz));
    float d = __fsub_rn(__fadd_rn(aw, qw), __fmul_rn(2.0f, dot));
    u32 ub = __float_as_uint(d);
    ub ^= (ub & 0x80000000u) ? 0xFFFFFFFFu : 0x80000000u;
    u64 key = ((u64)ub << 32) | (u32)n;
    if (key < arr[KD - 1]) {
      bool cg[KD];
#pragma unroll
      for (int i = 0; i < KD; ++i) cg[i] = arr[i] > key;
#pragma unroll
      for (int i = KD - 1; i >= 1; --i)
        arr[i] = cg[i - 1] ? arr[i - 1] : (cg[i] ? key : arr[i]);
      arr[0] = cg[0] ? key : arr[0];
    }
  }
  u64 mine = 0;
  for (int it = 0; it < 24; ++it) {
    u64 mw = wave_min_u64(arr[0]);
    if (lane == it) mine = mw;
    if (arr[0] == mw) {
#pragma unroll
      for (int i = 0; i < KD - 1; ++i) arr[i] = arr[i + 1];
      arr[KD - 1] = ~0ull;
    }
  }
  if (lane < 24) knn[row * 24 + lane] = (u16)(mine & 0xFFFFu);
}

// ---------------------------------------------------------------------------
// K3 (r17, unchanged): fused base-SA + multi-scale MLPs. blockIdx.y = 0 ->
// base (feat [rel_xyz|pts] 6->64 relu -> 64->128, K=16, out ch 0..127);
// blockIdx.y = 1..3 -> ms scale y-1 (rel_xyz 3->64 relu -> 64->128, K=8y,
// out ch 128y..128y+127). Branch is block-uniform. Staging gathers via
// float4 (USE4). Per-wave h2: thread owns 2 out channels, W2 rows in
// registers, h1 read as wave-uniform float4 broadcast.
// ---------------------------------------------------------------------------
template <int USE4>
__global__ __launch_bounds__(256) void k_mlp(
    const float* __restrict__ xyz, const float* __restrict__ pts,
    const float4* __restrict__ xyz4, const float4* __restrict__ pts4,
    const float* __restrict__ kp, const u16* __restrict__ knn,
    const float* __restrict__ W1, const float* __restrict__ b1,
    const float* __restrict__ W2, const float* __restrict__ b2,
    const float* __restrict__ msW1, const float* __restrict__ msb1,
    const float* __restrict__ msW2, const float* __restrict__ msb2,
    float* __restrict__ out) {
  __shared__ float smem[6688];
  int t = threadIdx.x, lane = t & 63, w = t >> 6;
  int b = blockIdx.x >> 6, s0 = (blockIdx.x & 63) * 8;
  if (blockIdx.y == 0) {
    float* sW1T = smem;          // [c][o] 6*64
    float* sb1 = smem + 384;     // 64
    float* sfeat = smem + 448;   // [row][k*6+c] 4*96
    float* sh1 = smem + 832;     // [row][k*64+o] 4*1024
    for (int i = t; i < 384; i += 256) {
      int o = i / 6, c = i - o * 6;
      sW1T[c * 64 + o] = W1[i];
    }
    if (t < 64) sb1[t] = b1[t];
    float wgtA[64], wgtB[64];
#pragma unroll
    for (int j = 0; j < 64; ++j) {
      wgtA[j] = W2[lane * 64 + j];
      wgtB[j] = W2[(lane + 64) * 64 + j];
    }
    float b2A = b2[lane], b2B = b2[lane + 64];
    __syncthreads();
    for (int g = 0; g < 2; ++g) {
      if (t < 128) {  // 64 (rr,k) pairs x 2 halves: h=0 xyz, h=1 pts
        int p = t >> 1, h = t & 1;
        int rr = p >> 4, k = p & 15;
        int s = s0 + g * 4 + rr, row = b * SS + s;
        int id = knn[row * 24 + k];  // first 16 of sorted top-24 = base KNN
        float* f = &sfeat[rr * 96 + k * 6];
        if (h == 0) {
          float qx, qy, qz;
          if constexpr (USE4) {
            float4 q = xyz4[(b << 13) + id];
            qx = q.x; qy = q.y; qz = q.z;
          } else {
            qx = xyz[b * N3 + id];
            qy = xyz[b * N3 + NN + id];
            qz = xyz[b * N3 + 2 * NN + id];
          }
          f[0] = __fsub_rn(qx, kp[b * 1536 + s]);
          f[1] = __fsub_rn(qy, kp[b * 1536 + SS + s]);
          f[2] = __fsub_rn(qz, kp[b * 1536 + 2 * SS + s]);
        } else {
          float px_, py_, pz_;
          if constexpr (USE4) {
            float4 q = pts4[(b << 13) + id];
            px_ = q.x; py_ = q.y; pz_ = q.z;
          } else {
            px_ = pts[b * N3 + id];
            py_ = pts[b * N3 + NN + id];
            pz_ = pts[b * N3 + 2 * NN + id];
          }
          f[3] = px_;
          f[4] = py_;
          f[5] = pz_;
        }
      }
      __syncthreads();
#pragma unroll
      for (int m = 0; m < 16; ++m) {  // 4 rows x 1024 h1 entries / 256 thr
        int u = m * 256 + t;
        int rr = u >> 10, rem = u & 1023, k = rem >> 6, o = rem & 63;
        float acc = sb1[o];
#pragma unroll
        for (int c = 0; c < 6; ++c) acc = fmaf(sfeat[rr * 96 + k * 6 + c], sW1T[c * 64 + o], acc);
        sh1[rr * 1024 + k * 64 + o] = fmaxf(acc, 0.f);
      }
      __syncthreads();
      float bestA = -1e30f, bestB = -1e30f;
#pragma unroll
      for (int k = 0; k < 16; ++k) {
        const float4* h4 = (const float4*)&sh1[w * 1024 + k * 64];  // wave-uniform bcast
        float a0 = 0.f, a1 = 0.f;
#pragma unroll
        for (int j = 0; j < 16; ++j) {
          float4 hv = h4[j];
          a0 = fmaf(hv.x, wgtA[4 * j], a0);
          a0 = fmaf(hv.y, wgtA[4 * j + 1], a0);
          a0 = fmaf(hv.z, wgtA[4 * j + 2], a0);
          a0 = fmaf(hv.w, wgtA[4 * j + 3], a0);
          a1 = fmaf(hv.x, wgtB[4 * j], a1);
          a1 = fmaf(hv.y, wgtB[4 * j + 1], a1);
          a1 = fmaf(hv.z, wgtB[4 * j + 2], a1);
          a1 = fmaf(hv.w, wgtB[4 * j + 3], a1);
        }
        bestA = fmaxf(bestA, a0);
        bestB = fmaxf(bestB, a1);
      }
      int s = s0 + g * 4 + w;
      out[24576 + b * 262144 + lane * 512 + s] = bestA + b2A;
      out[24576 + b * 262144 + (lane + 64) * 512 + s] = bestB + b2B;
      __syncthreads();  // protect sfeat/sh1 before next group overwrites
    }
  } else {
    int scale = blockIdx.y - 1;
    int kk = 8 * (scale + 1);
    float* sW1T = smem;          // [c][o] 3*64
    float* sb1 = smem + 192;     // 64
    float* sfeat = smem + 256;   // [row][k*3+c] 4*72
    float* sh1 = smem + 544;     // [row][k*64+o] 4*1536
    const float* W1s = msW1 + scale * 192;
    for (int i = t; i < 192; i += 256) {
      int o = i / 3, c = i - o * 3;
      sW1T[c * 64 + o] = W1s[i];
    }
    if (t < 64) sb1[t] = msb1[scale * 64 + t];
    float wgtA[64], wgtB[64];
#pragma unroll
    for (int j = 0; j < 64; ++j) {
      wgtA[j] = msW2[scale * 8192 + lane * 64 + j];
      wgtB[j] = msW2[scale * 8192 + (lane + 64) * 64 + j];
    }
    float b2A = msb2[scale * 128 + lane], b2B = msb2[scale * 128 + lane + 64];
    __syncthreads();
    int co = 128 * (scale + 1);
    for (int g = 0; g < 2; ++g) {
      if (t < 96) {  // 4 rows x 24 slots (stage all 24; h1 reads only k<kk)
        int rr = t / 24, k = t - rr * 24;  // constant divisor -> mul-shift
        int s = s0 + g * 4 + rr, row = b * SS + s;
        int id = knn[row * 24 + k];
        float qx, qy, qz;
        if constexpr (USE4) {
          float4 q = xyz4[(b << 13) + id];
          qx = q.x; qy = q.y; qz = q.z;
        } else {
          qx = xyz[b * N3 + id];
          qy = xyz[b * N3 + NN + id];
          qz = xyz[b * N3 + 2 * NN + id];
        }
        float* f = &sfeat[rr * 72 + k * 3];
        f[0] = __fsub_rn(qx, kp[b * 1536 + s]);
        f[1] = __fsub_rn(qy, kp[b * 1536 + SS + s]);
        f[2] = __fsub_rn(qz, kp[b * 1536 + 2 * SS + s]);
      }
      __syncthreads();
      for (int rr = 0; rr < 4; ++rr) {  // h1 for kk*64 entries per row
        for (int u = t; u < kk * 64; u += 256) {
          int k = u >> 6, o = u & 63;
          float acc = sb1[o];
          acc = fmaf(sfeat[rr * 72 + k * 3 + 0], sW1T[o], acc);
          acc = fmaf(sfeat[rr * 72 + k * 3 + 1], sW1T[64 + o], acc);
          acc = fmaf(sfeat[rr * 72 + k * 3 + 2], sW1T[128 + o], acc);
          sh1[rr * 1536 + k * 64 + o] = fmaxf(acc, 0.f);
        }
      }
      __syncthreads();
      float bestA = -1e30f, bestB = -1e30f;
      for (int k = 0; k < kk; ++k) {  // kk uniform across block -> no divergence
        const float4* h4 = (const float4*)&sh1[w * 1536 + k * 64];
        float a0 = 0.f, a1 = 0.f;
#pragma unroll
        for (int j = 0; j < 16; ++j) {
          float4 hv = h4[j];
          a0 = fmaf(hv.x, wgtA[4 * j], a0);
          a0 = fmaf(hv.y, wgtA[4 * j + 1], a0);
          a0 = fmaf(hv.z, wgtA[4 * j + 2], a0);
          a0 = fmaf(hv.w, wgtA[4 * j + 3], a0);
          a1 = fmaf(hv.x, wgtB[4 * j], a1);
          a1 = fmaf(hv.y, wgtB[4 * j + 1], a1);
          a1 = fmaf(hv.z, wgtB[4 * j + 2], a1);
          a1 = fmaf(hv.w, wgtB[4 * j + 3], a1);
        }
        bestA = fmaxf(bestA, a0);
        bestB = fmaxf(bestB, a1);
      }
      int s = s0 + g * 4 + w;
      out[24576 + b * 262144 + (co + lane) * 512 + s] = bestA + b2A;
      out[24576 + b * 262144 + (co + lane + 64) * 512 + s] = bestB + b2B;
      __syncthreads();
    }
  }
}

// ---------------------------------------------------------------------------
extern "C" void kernel_launch(void* const* d_in, const int* in_sizes, int n_in,
                              void* d_out, int out_size, void* d_ws, size_t ws_size,
                              hipStream_t stream) {
  const float* xyz = (const float*)d_in[0];    // l0_xyz  [B,3,N] f32
  const float* pts = (const float*)d_in[1];    // l0_points
  const float* sa_W1 = (const float*)d_in[2];  // [64,6]
  const float* sa_b1 = (const float*)d_in[3];  // [64]
  const float* sa_W2 = (const float*)d_in[4];  // [128,64]
  const float* sa_b2 = (const float*)d_in[5];  // [128]
  const float* ms_W1 = (const float*)d_in[6];  // [3,64,3]
  const float* ms_b1 = (const float*)d_in[7];  // [3,64]
  const float* ms_W2 = (const float*)d_in[8];  // [3,128,64]
  const float* ms_b2 = (const float*)d_in[9];  // [3,128]
  float* out = (float*)d_out;
  const float* kp = (const float*)d_out;  // keypoints written by k_fps

  // workspace: knn u16[B*S*24] = 393216 B, then xyz4/pts4 float4[B*N] = 2 MB each
  u16* knn = (u16*)d_ws;
  float4* xyz4 = (float4*)((char*)d_ws + 393216);
  float4* pts4 = xyz4 + BB * NN;
  const size_t need4 = 393216 + (size_t)2 * BB * NN * sizeof(float4);
  const bool use4 = ws_size >= need4;

  if (use4) k_prep<<<BB * NN / 256, 256, 0, stream>>>(xyz, pts, xyz4, pts4);
  k_fps<<<BB, 512, 0, stream>>>(xyz, out);
  if (use4) {
    k_knn_blk<<<BB * SS, 256, 0, stream>>>(xyz4, kp, knn);
    k_mlp<1><<<dim3(BB * 64, 4), 256, 0, stream>>>(xyz, pts, xyz4, pts4, kp, knn,
                                                   sa_W1, sa_b1, sa_W2, sa_b2,
                                                   ms_W1, ms_b1, ms_W2, ms_b2, out);
  } else {
    k_knn_solo<<<(BB * SS) / 4, 256, 0, stream>>>(xyz, kp, knn);
    k_mlp<0><<<dim3(BB * 64, 4), 256, 0, stream>>>(xyz, pts, xyz4, pts4, kp, knn,
                                                   sa_W1, sa_b1, sa_W2, sa_b2,
                                                   ms_W1, ms_b1, ms_W2, ms_b2, out);
  }
}

// Round 9
// 878.834 us; speedup vs baseline: 1.4177x; 1.0290x over previous
//
#include <hip/hip_runtime.h>

#define BB 16
#define NN 8192
#define SS 512
#define N3 (3 * NN)  // 24576 elements per batch per tensor
#define KD 14        // per-lane depth for the SOLO (1-wave-per-row) fallback
#define KDB 7        // per-lane depth for the block-per-row kernel (32 pts/lane)

typedef unsigned short u16;
typedef unsigned int u32;
typedef unsigned long long u64;
typedef float v2f __attribute__((ext_vector_type(2)));

// Packed fp32 ops (VOP3P, 2 points/inst). Per-half rounding is IEEE rn —
// bit-identical to scalar __fadd_rn/__fmul_rn.
__device__ __forceinline__ v2f pk_add(v2f a, v2f b) {
  v2f r;
  asm("v_pk_add_f32 %0, %1, %2" : "=v"(r) : "v"(a), "v"(b));
  return r;
}
__device__ __forceinline__ v2f pk_mul(v2f a, v2f b) {
  v2f r;
  asm("v_pk_mul_f32 %0, %1, %2" : "=v"(r) : "v"(a), "v"(b));
  return r;
}

// u64 max step over a DPP lane-shift (FPS): old=0 is the max identity for our
// positive keys.
template <int CTRL>
__device__ __forceinline__ u64 dpp_maxk(u64 k) {
  u32 lo = (u32)k, hi = (u32)(k >> 32);
  u32 slo = (u32)__builtin_amdgcn_update_dpp(0, (int)lo, CTRL, 0xf, 0xf, false);
  u32 shi = (u32)__builtin_amdgcn_update_dpp(0, (int)hi, CTRL, 0xf, 0xf, false);
  u64 s = ((u64)shi << 32) | (u64)slo;
  return (s > k) ? s : k;
}
// u64 MIN step over a DPP lane-shift (KNN merges): old=self is the min
// identity.
template <int CTRL>
__device__ __forceinline__ u64 dpp_mink(u64 k) {
  u32 lo = (u32)k, hi = (u32)(k >> 32);
  u32 slo = (u32)__builtin_amdgcn_update_dpp((int)lo, (int)lo, CTRL, 0xf, 0xf, false);
  u32 shi = (u32)__builtin_amdgcn_update_dpp((int)hi, (int)hi, CTRL, 0xf, 0xf, false);
  u64 s = ((u64)shi << 32) | (u64)slo;
  return (s < k) ? s : k;
}
__device__ __forceinline__ u64 maxk(u64 a, u64 b) { return (a > b) ? a : b; }

// wave-min of `m` to ALL-lanes-usable form: 6-step DPP chain -> lane63, then
// 2 readlanes -> SGPR-uniform u64.
__device__ __forceinline__ u64 wave_min_u64(u64 m) {
  m = dpp_mink<0x111>(m);  // row_shr:1
  m = dpp_mink<0x112>(m);  // row_shr:2
  m = dpp_mink<0x114>(m);  // row_shr:4
  m = dpp_mink<0x118>(m);  // row_shr:8
  m = dpp_mink<0x142>(m);  // row_bcast:15
  m = dpp_mink<0x143>(m);  // row_bcast:31 -> lane63 = wave min
  u32 mlo = (u32)__builtin_amdgcn_readlane((int)(u32)m, 63);
  u32 mhi = (u32)__builtin_amdgcn_readlane((int)(u32)(m >> 32), 63);
  return ((u64)mhi << 32) | (u64)mlo;
}

// ---------------------------------------------------------------------------
// K0: precompute per-point float4 {x,y,z,|q|^2} for xyz and {x,y,z,0} for
// l0_points into workspace. |q|^2 uses the EXACT rn tree -> bits unchanged
// downstream.
// ---------------------------------------------------------------------------
__global__ __launch_bounds__(256) void k_prep(const float* __restrict__ xyz,
                                              const float* __restrict__ pts,
                                              float4* __restrict__ xyz4,
                                              float4* __restrict__ pts4) {
  int i = blockIdx.x * 256 + threadIdx.x;  // < BB*NN
  int b = i >> 13, n = i & (NN - 1);
  const float* xb = xyz + b * N3;
  float x = xb[n], y = xb[NN + n], z = xb[2 * NN + n];
  float w = __fadd_rn(__fadd_rn(__fmul_rn(x, x), __fmul_rn(y, y)), __fmul_rn(z, z));
  xyz4[i] = make_float4(x, y, z, w);
  const float* pb = pts + b * N3;
  pts4[i] = make_float4(pb[n], pb[NN + n], pb[2 * NN + n], 0.f);
}

// ---------------------------------------------------------------------------
// K1: farthest point sampling, fp32, bit-exact vs numpy. r16 structure,
// UNCHANGED (508us, ~79% of the 16-CU issue cap; 16 blocks pinned to 16 CUs
// is the structural limit — overlap attempts r18/r19 both regressed on
// agent-scope store drains + acquire-poll invalidation traffic).
// ---------------------------------------------------------------------------
__global__ __attribute__((amdgpu_flat_work_group_size(512, 512),
                          amdgpu_waves_per_eu(2, 2)))
void k_fps(const float* __restrict__ xyz, float* __restrict__ out_kp) {
  __shared__ float sxyz[NN * 3];  // [idx][x,y,z]
  __shared__ int sIdx[SS];
  __shared__ u64 rkey[2][8];
  int b = blockIdx.x, t = threadIdx.x;
  const float* base = xyz + b * N3;
  v2f px[8], py[8], pz[8], dm[8];
#pragma unroll
  for (int j = 0; j < 8; ++j) {
    int n0 = j * 1024 + t, n1 = n0 + 512;  // coalesced, disjoint cover [0,8192)
    px[j] = v2f{base[n0], base[n1]};
    py[j] = v2f{base[NN + n0], base[NN + n1]};
    pz[j] = v2f{base[2 * NN + n0], base[2 * NN + n1]};
    dm[j] = v2f{1e10f, 1e10f};
    sxyz[n0 * 3 + 0] = px[j].x;  // stage AoS copy for center re-loads
    sxyz[n0 * 3 + 1] = py[j].x;
    sxyz[n0 * 3 + 2] = pz[j].x;
    sxyz[n1 * 3 + 0] = px[j].y;
    sxyz[n1 * 3 + 1] = py[j].y;
    sxyz[n1 * 3 + 2] = pz[j].y;
  }
#pragma unroll
  for (int j = 0; j < 8; ++j) {
    // Opaque def: blocks rematerialization of the global loads.
    asm volatile("" : "+v"(px[j]), "+v"(py[j]), "+v"(pz[j]));
  }
  // staging writes become visible at iter-0's barrier, before first LDS read
  float cx = base[0], cy = base[NN], cz = base[2 * NN];
  int far = 0;
  int lane = t & 63, w = t >> 6;
  u32 tb = (u32)(NN - t);  // candidate base: cand = NN - gidx (1..8192; 0=none)
  for (int it = 0; it < SS; ++it) {
    if (t == 0) sIdx[it] = far;  // scan emits carry BEFORE update: idx[0]=0
    // negated center, broadcast to both halves (a + (-c) == a - c exactly)
    v2f ncx = v2f{-cx, -cx}, ncy = v2f{-cy, -cy}, ncz = v2f{-cz, -cz};
    float vmax = 0.0f;
#pragma unroll
    for (int j = 0; j < 8; ++j) {
      v2f dx = pk_add(px[j], ncx);
      v2f dy = pk_add(py[j], ncy);
      v2f dz = pk_add(pz[j], ncz);
      v2f xx = pk_mul(dx, dx);
      v2f yy = pk_mul(dy, dy);
      v2f s = pk_add(xx, yy);
      v2f zz = pk_mul(dz, dz);
      v2f d = pk_add(s, zz);  // ((dx^2+dy^2)+dz^2), numpy tree per half
      float a0 = fminf(dm[j].x, d.x);
      float a1 = fminf(dm[j].y, d.y);
      dm[j].x = a0;
      dm[j].y = a1;
      vmax = fmaxf(vmax, fmaxf(a0, a1));  // max3-foldable
    }
    // thread-local find vs this thread's OWN max: exact bit-equality (vmax IS
    // one of this thread's dm values). Descending gidx order -> LAST write =
    // lowest gidx within the thread.
    u32 cand = 0;
#pragma unroll
    for (int j = 7; j >= 0; --j) {
      u32 v1 = tb - (u32)(j * 1024 + 512);  // cand for .y half (higher gidx)
      u32 v0 = tb - (u32)(j * 1024);        // cand for .x half
      cand = (dm[j].y == vmax) ? v1 : cand;
      cand = (dm[j].x == vmax) ? v0 : cand;
    }
    // one packed key per thread; 6-step DPP u64 max chain -> lane63 holds the
    // wave best (max dist, tie -> max cand = min gidx). VALU pipe only.
    u64 key = ((u64)__float_as_uint(vmax) << 32) | cand;
    key = dpp_maxk<0x111>(key);  // row_shr:1
    key = dpp_maxk<0x112>(key);  // row_shr:2
    key = dpp_maxk<0x114>(key);  // row_shr:4
    key = dpp_maxk<0x118>(key);  // row_shr:8
    key = dpp_maxk<0x142>(key);  // row_bcast:15
    key = dpp_maxk<0x143>(key);  // row_bcast:31 -> lane63 = wave max
    int pb = it & 1;  // parity double-buffer: safe with one barrier/iter
    if (lane == 63) rkey[pb][w] = key;
    __syncthreads();  // the only barrier per iteration
    // block reduce over 8 wave keys: every thread broadcast-reads all 8 slots
    // + redundant VALU tree. No cross-lane ops at all in this phase.
    u64 k0 = rkey[pb][0], k1 = rkey[pb][1];
    u64 k2 = rkey[pb][2], k3 = rkey[pb][3];
    u64 k4 = rkey[pb][4], k5 = rkey[pb][5];
    u64 k6 = rkey[pb][6], k7 = rkey[pb][7];
    u64 kg = maxk(maxk(maxk(k0, k1), maxk(k2, k3)),
                  maxk(maxk(k4, k5), maxk(k6, k7)));
    far = NN - (int)(u32)(kg & 0xffffffffu);
    // broadcast ds_read of the winner's coords (all lanes same address)
    cx = sxyz[far * 3 + 0];
    cy = sxyz[far * 3 + 1];
    cz = sxyz[far * 3 + 2];
  }
  __syncthreads();
  for (int i = t; i < SS; i += 512) {
    int id = sIdx[i];
    out_kp[b * 1536 + i] = base[id];  // exact fp32 copies
    out_kp[b * 1536 + SS + i] = base[NN + id];
    out_kp[b * 1536 + 2 * SS + i] = base[2 * NN + id];
  }
}

// ---------------------------------------------------------------------------
// K2 (r21, unchanged): one ROW per 256-thread BLOCK. 32 pts/lane, KDB=7
// (failure odds ~8e-8/run). 3-level exact min-extract merge -> bit-identical
// to the 1-wave version. 985 -> 904 us win.
// ---------------------------------------------------------------------------
__global__ __launch_bounds__(256) void k_knn_blk(const float4* __restrict__ xyz4,
                                                 const float* __restrict__ kp,
                                                 u16* __restrict__ knn) {
  __shared__ u64 skeys[96];
  int t = threadIdx.x, lane = t & 63, w = t >> 6;
  int b = blockIdx.x >> 9, s = blockIdx.x & (SS - 1);
  const float4* base4 = xyz4 + (b << 13);
  float ax = kp[b * 1536 + s];
  float ay = kp[b * 1536 + SS + s];
  float az = kp[b * 1536 + 2 * SS + s];
  float aw = __fadd_rn(__fadd_rn(__fmul_rn(ax, ax), __fmul_rn(ay, ay)), __fmul_rn(az, az));
  u64 arr[KDB];
#pragma unroll
  for (int i = 0; i < KDB; ++i) arr[i] = ~0ull;
  for (int c = 0; c < 32; ++c) {
    int n = c * 256 + t;  // coalesced across the block, disjoint cover
    float4 q = base4[n];  // one dwordx4
    float dot = __fadd_rn(__fadd_rn(__fmul_rn(ax, q.x), __fmul_rn(ay, q.y)),
                          __fmul_rn(az, q.z));
    float d = __fsub_rn(__fadd_rn(aw, q.w), __fmul_rn(2.0f, dot));
    u32 ub = __float_as_uint(d);
    ub ^= (ub & 0x80000000u) ? 0xFFFFFFFFu : 0x80000000u;  // order-preserving map
    u64 key = ((u64)ub << 32) | (u32)n;
    if (key < arr[KDB - 1]) {  // sorted insert, CSE'd conditions
      bool cg[KDB];
#pragma unroll
      for (int i = 0; i < KDB; ++i) cg[i] = arr[i] > key;
#pragma unroll
      for (int i = KDB - 1; i >= 1; --i)
        arr[i] = cg[i - 1] ? arr[i - 1] : (cg[i] ? key : arr[i]);
      arr[0] = cg[0] ? key : arr[0];
    }
  }
  // phase A: per-wave merge of 64 sorted lists -> wave's sorted top-24
  u64 mine = 0;
  for (int it = 0; it < 24; ++it) {
    u64 mw = wave_min_u64(arr[0]);
    if (lane == it) mine = mw;
    if (arr[0] == mw) {  // unique keys -> exactly one popper
#pragma unroll
      for (int i = 0; i < KDB - 1; ++i) arr[i] = arr[i + 1];
      arr[KDB - 1] = ~0ull;
    }
  }
  if (lane < 24) skeys[w * 24 + lane] = mine;
  __syncthreads();
  // phase B: wave 0 merges the 4 sorted 24-lists (96 unique keys)
  if (w == 0) {
    u64 a = skeys[lane];
    u64 b2 = (lane < 32) ? skeys[64 + lane] : ~0ull;
    u64 lo = (a < b2) ? a : b2;
    u64 hi = (a < b2) ? b2 : a;
    u64 outk = 0;
    for (int it = 0; it < 24; ++it) {
      u64 mw = wave_min_u64(lo);
      if (lane == it) outk = mw;
      if (lo == mw) {
        lo = hi;
        hi = ~0ull;
      }
    }
    if (lane < 24) knn[blockIdx.x * 24 + lane] = (u16)(outk & 0xFFFFu);
  }
}

// ---------------------------------------------------------------------------
// Fallback solo KNN (workspace too small for float4): r17 scalar path,
// 1 wave per row, KD=14.
// ---------------------------------------------------------------------------
__global__ __launch_bounds__(256) void k_knn_solo(const float* __restrict__ xyz,
                                                  const float* __restrict__ kp,
                                                  u16* __restrict__ knn) {
  int t = threadIdx.x;
  int row = blockIdx.x * 4 + (t >> 6);
  int lane = t & 63;
  int b = row >> 9, s = row & (SS - 1);
  const float* base = xyz + b * N3;
  float ax = kp[b * 1536 + s];
  float ay = kp[b * 1536 + SS + s];
  float az = kp[b * 1536 + 2 * SS + s];
  float aw = __fadd_rn(__fadd_rn(__fmul_rn(ax, ax), __fmul_rn(ay, ay)), __fmul_rn(az, az));
  u64 arr[KD];
#pragma unroll
  for (int i = 0; i < KD; ++i) arr[i] = ~0ull;
  for (int c = 0; c < 128; ++c) {
    int n = c * 64 + lane;
    float qx = base[n], qy = base[NN + n], qz = base[2 * NN + n];
    float qw = __fadd_rn(__fadd_rn(__fmul_rn(qx, qx), __fmul_rn(qy, qy)), __fmul_rn(qz, qz));
    float dot = __fadd_rn(__fadd_rn(__fmul_rn(ax, qx), __fmul_rn(ay, qy)), __fmul_rn(az, qz));
    float d = __fsub_rn(__fadd_rn(aw, qw), __fmul_rn(2.0f, dot));
    u32 ub = __float_as_uint(d);
    ub ^= (ub & 0x80000000u) ? 0xFFFFFFFFu : 0x80000000u;
    u64 key = ((u64)ub << 32) | (u32)n;
    if (key < arr[KD - 1]) {
      bool cg[KD];
#pragma unroll
      for (int i = 0; i < KD; ++i) cg[i] = arr[i] > key;
#pragma unroll
      for (int i = KD - 1; i >= 1; --i)
        arr[i] = cg[i - 1] ? arr[i - 1] : (cg[i] ? key : arr[i]);
      arr[0] = cg[0] ? key : arr[0];
    }
  }
  u64 mine = 0;
  for (int it = 0; it < 24; ++it) {
    u64 mw = wave_min_u64(arr[0]);
    if (lane == it) mine = mw;
    if (arr[0] == mw) {
#pragma unroll
      for (int i = 0; i < KD - 1; ++i) arr[i] = arr[i + 1];
      arr[KD - 1] = ~0ull;
    }
  }
  if (lane < 24) knn[row * 24 + lane] = (u16)(mine & 0xFFFFu);
}

// ---------------------------------------------------------------------------
// K3 (r22): fused base-SA + multi-scale MLPs. blockIdx.y = 0 -> base; 1..3 ->
// ms scale y-1. SAME h1/h2 math and summation order as r17 (bit-identical).
// r22 change — kill the W2 gather storm: r17's wgtA/wgtB (128 floats) showed
// VGPR_Count=108 < 128 ==> regalloc did NOT keep the weights resident; the
// __restrict const global loads are rematerializable, so the compiler
// re-issues them in the hot k-loop as 64-lane stride-256B gathers (each inst
// ~64 L1 transactions; ~1/cy L1 port ==> the ~150us gap vs the 60us issue
// model). Fix: stage W2 TRANSPOSED into LDS once per block (coalesced global
// reads; LDS writes stride 130 words -> bank (2*lane+row)%32 = 2-way = free),
// fill wgtA/wgtB from LDS (2-way, ds_read2-pairable), then ASM-PIN all 128
// registers (opaque redef blocks remat — the proven k_fps px-pinning trick).
// The W2T buffer is dead after the fill, so it ALIASES the sfeat/sh1 region
// (union, 35KB total). Occupancy drops to ~2 waves/SIMD at ~170 VGPR — fine:
// h2's two 64-deep fma chains already saturate a SIMD's issue at 1 wave.
// ---------------------------------------------------------------------------
template <int USE4>
__global__ __launch_bounds__(256) void k_mlp(
    const float* __restrict__ xyz, const float* __restrict__ pts,
    const float4* __restrict__ xyz4, const float4* __restrict__ pts4,
    const float* __restrict__ kp, const u16* __restrict__ knn,
    const float* __restrict__ W1, const float* __restrict__ b1,
    const float* __restrict__ W2, const float* __restrict__ b2,
    const float* __restrict__ msW1, const float* __restrict__ msb1,
    const float* __restrict__ msW2, const float* __restrict__ msb2,
    float* __restrict__ out) {
  __shared__ float smem[448 + 8320];  // persistent 448 | big 8320 (35KB)
  float* sW1T = smem;                 // [c][o] (384 base / 192 ms)
  float* sb1 = smem + 384;            // 64
  float* big = smem + 448;            // W2T during init; sfeat|sh1 in groups
  int t = threadIdx.x, lane = t & 63, w = t >> 6;
  int b = blockIdx.x >> 6, s0 = (blockIdx.x & 63) * 8;
  int scale = (int)blockIdx.y - 1;  // -1 for base plane
  float b2A, b2B;
  const float* W2src;
  if (blockIdx.y == 0) {
    for (int i = t; i < 384; i += 256) {
      int o = i / 6, c = i - o * 6;
      sW1T[c * 64 + o] = W1[i];
    }
    if (t < 64) sb1[t] = b1[t];
    W2src = W2;
    b2A = b2[lane];
    b2B = b2[lane + 64];
  } else {
    const float* W1s = msW1 + scale * 192;
    for (int i = t; i < 192; i += 256) {
      int o = i / 3, c = i - o * 3;
      sW1T[c * 64 + o] = W1s[i];
    }
    if (t < 64) sb1[t] = msb1[scale * 64 + t];
    W2src = msW2 + scale * 8192;
    b2A = msb2[scale * 128 + lane];
    b2B = msb2[scale * 128 + lane + 64];
  }
  // Stage W2 transposed: big[j*130 + row]. Global reads coalesced (32/thread);
  // per wave row is fixed, j = lane -> write bank (2*lane+row)%32 = 2-way.
  for (int i = t; i < 8192; i += 256) {
    int row = i >> 6, j = i & 63;
    big[j * 130 + row] = W2src[i];
  }
  __syncthreads();
  float wgtA[64], wgtB[64];
#pragma unroll
  for (int j = 0; j < 64; ++j) {
    wgtA[j] = big[j * 130 + lane];       // bank (2j+lane)%32: 2-way, free
    wgtB[j] = big[j * 130 + 64 + lane];  // ds_read2-pairable with the above
  }
#pragma unroll
  for (int j = 0; j < 64; ++j) {
    // Opaque def: forces true VGPR residency (blocks remat/spill-reload).
    asm volatile("" : "+v"(wgtA[j]), "+v"(wgtB[j]));
  }
  __syncthreads();  // all reg fills done before groups overwrite `big`
  if (blockIdx.y == 0) {
    // ---------------- base plane ----------------
    float* sfeat = big;        // [row][k*6+c] 4*96
    float* sh1 = big + 384;    // [row][k*64+o] 4*1024 (16B-aligned: 3328B)
    for (int g = 0; g < 2; ++g) {
      if (t < 128) {  // 64 (rr,k) pairs x 2 halves: h=0 xyz, h=1 pts
        int p = t >> 1, h = t & 1;
        int rr = p >> 4, k = p & 15;
        int s = s0 + g * 4 + rr, row = b * SS + s;
        int id = knn[row * 24 + k];  // first 16 of sorted top-24 = base KNN
        float* f = &sfeat[rr * 96 + k * 6];
        if (h == 0) {
          float qx, qy, qz;
          if constexpr (USE4) {
            float4 q = xyz4[(b << 13) + id];
            qx = q.x; qy = q.y; qz = q.z;
          } else {
            qx = xyz[b * N3 + id];
            qy = xyz[b * N3 + NN + id];
            qz = xyz[b * N3 + 2 * NN + id];
          }
          f[0] = __fsub_rn(qx, kp[b * 1536 + s]);
          f[1] = __fsub_rn(qy, kp[b * 1536 + SS + s]);
          f[2] = __fsub_rn(qz, kp[b * 1536 + 2 * SS + s]);
        } else {
          float px_, py_, pz_;
          if constexpr (USE4) {
            float4 q = pts4[(b << 13) + id];
            px_ = q.x; py_ = q.y; pz_ = q.z;
          } else {
            px_ = pts[b * N3 + id];
            py_ = pts[b * N3 + NN + id];
            pz_ = pts[b * N3 + 2 * NN + id];
          }
          f[3] = px_;
          f[4] = py_;
          f[5] = pz_;
        }
      }
      __syncthreads();
#pragma unroll
      for (int m = 0; m < 16; ++m) {  // 4 rows x 1024 h1 entries / 256 thr
        int u = m * 256 + t;
        int rr = u >> 10, rem = u & 1023, k = rem >> 6, o = rem & 63;
        float acc = sb1[o];
#pragma unroll
        for (int c = 0; c < 6; ++c) acc = fmaf(sfeat[rr * 96 + k * 6 + c], sW1T[c * 64 + o], acc);
        sh1[rr * 1024 + k * 64 + o] = fmaxf(acc, 0.f);
      }
      __syncthreads();
      float bestA = -1e30f, bestB = -1e30f;
#pragma unroll
      for (int k = 0; k < 16; ++k) {
        const float4* h4 = (const float4*)&sh1[w * 1024 + k * 64];  // wave-uniform bcast
        float a0 = 0.f, a1 = 0.f;
#pragma unroll
        for (int j = 0; j < 16; ++j) {
          float4 hv = h4[j];
          a0 = fmaf(hv.x, wgtA[4 * j], a0);
          a0 = fmaf(hv.y, wgtA[4 * j + 1], a0);
          a0 = fmaf(hv.z, wgtA[4 * j + 2], a0);
          a0 = fmaf(hv.w, wgtA[4 * j + 3], a0);
          a1 = fmaf(hv.x, wgtB[4 * j], a1);
          a1 = fmaf(hv.y, wgtB[4 * j + 1], a1);
          a1 = fmaf(hv.z, wgtB[4 * j + 2], a1);
          a1 = fmaf(hv.w, wgtB[4 * j + 3], a1);
        }
        bestA = fmaxf(bestA, a0);
        bestB = fmaxf(bestB, a1);
      }
      int s = s0 + g * 4 + w;
      out[24576 + b * 262144 + lane * 512 + s] = bestA + b2A;
      out[24576 + b * 262144 + (lane + 64) * 512 + s] = bestB + b2B;
      __syncthreads();  // protect sfeat/sh1 before next group overwrites
    }
  } else {
    // ---------------- ms planes (kk = 8*(scale+1)) ----------------
    int kk = 8 * (scale + 1);
    float* sfeat = big;        // [row][k*3+c] 4*72
    float* sh1 = big + 288;    // [row][k*64+o] 4*1536 (16B-aligned: 2944B)
    int co = 128 * (scale + 1);
    for (int g = 0; g < 2; ++g) {
      if (t < 96) {  // 4 rows x 24 slots (stage all 24; h1 reads only k<kk)
        int rr = t / 24, k = t - rr * 24;  // constant divisor -> mul-shift
        int s = s0 + g * 4 + rr, row = b * SS + s;
        int id = knn[row * 24 + k];
        float qx, qy, qz;
        if constexpr (USE4) {
          float4 q = xyz4[(b << 13) + id];
          qx = q.x; qy = q.y; qz = q.z;
        } else {
          qx = xyz[b * N3 + id];
          qy = xyz[b * N3 + NN + id];
          qz = xyz[b * N3 + 2 * NN + id];
        }
        float* f = &sfeat[rr * 72 + k * 3];
        f[0] = __fsub_rn(qx, kp[b * 1536 + s]);
        f[1] = __fsub_rn(qy, kp[b * 1536 + SS + s]);
        f[2] = __fsub_rn(qz, kp[b * 1536 + 2 * SS + s]);
      }
      __syncthreads();
      for (int rr = 0; rr < 4; ++rr) {  // h1 for kk*64 entries per row
        for (int u = t; u < kk * 64; u += 256) {
          int k = u >> 6, o = u & 63;
          float acc = sb1[o];
          acc = fmaf(sfeat[rr * 72 + k * 3 + 0], sW1T[o], acc);
          acc = fmaf(sfeat[rr * 72 + k * 3 + 1], sW1T[64 + o], acc);
          acc = fmaf(sfeat[rr * 72 + k * 3 + 2], sW1T[128 + o], acc);
          sh1[rr * 1536 + k * 64 + o] = fmaxf(acc, 0.f);
        }
      }
      __syncthreads();
      float bestA = -1e30f, bestB = -1e30f;
      for (int k = 0; k < kk; ++k) {  // kk uniform across block -> no divergence
        const float4* h4 = (const float4*)&sh1[w * 1536 + k * 64];
        float a0 = 0.f, a1 = 0.f;
#pragma unroll
        for (int j = 0; j < 16; ++j) {
          float4 hv = h4[j];
          a0 = fmaf(hv.x, wgtA[4 * j], a0);
          a0 = fmaf(hv.y, wgtA[4 * j + 1], a0);
          a0 = fmaf(hv.z, wgtA[4 * j + 2], a0);
          a0 = fmaf(hv.w, wgtA[4 * j + 3], a0);
          a1 = fmaf(hv.x, wgtB[4 * j], a1);
          a1 = fmaf(hv.y, wgtB[4 * j + 1], a1);
          a1 = fmaf(hv.z, wgtB[4 * j + 2], a1);
          a1 = fmaf(hv.w, wgtB[4 * j + 3], a1);
        }
        bestA = fmaxf(bestA, a0);
        bestB = fmaxf(bestB, a1);
      }
      int s = s0 + g * 4 + w;
      out[24576 + b * 262144 + (co + lane) * 512 + s] = bestA + b2A;
      out[24576 + b * 262144 + (co + lane + 64) * 512 + s] = bestB + b2B;
      __syncthreads();
    }
  }
}

// ---------------------------------------------------------------------------
extern "C" void kernel_launch(void* const* d_in, const int* in_sizes, int n_in,
                              void* d_out, int out_size, void* d_ws, size_t ws_size,
                              hipStream_t stream) {
  const float* xyz = (const float*)d_in[0];    // l0_xyz  [B,3,N] f32
  const float* pts = (const float*)d_in[1];    // l0_points
  const float* sa_W1 = (const float*)d_in[2];  // [64,6]
  const float* sa_b1 = (const float*)d_in[3];  // [64]
  const float* sa_W2 = (const float*)d_in[4];  // [128,64]
  const float* sa_b2 = (const float*)d_in[5];  // [128]
  const float* ms_W1 = (const float*)d_in[6];  // [3,64,3]
  const float* ms_b1 = (const float*)d_in[7];  // [3,64]
  const float* ms_W2 = (const float*)d_in[8];  // [3,128,64]
  const float* ms_b2 = (const float*)d_in[9];  // [3,128]
  float* out = (float*)d_out;
  const float* kp = (const float*)d_out;  // keypoints written by k_fps

  // workspace: knn u16[B*S*24] = 393216 B, then xyz4/pts4 float4[B*N] = 2 MB each
  u16* knn = (u16*)d_ws;
  float4* xyz4 = (float4*)((char*)d_ws + 393216);
  float4* pts4 = xyz4 + BB * NN;
  const size_t need4 = 393216 + (size_t)2 * BB * NN * sizeof(float4);
  const bool use4 = ws_size >= need4;

  if (use4) k_prep<<<BB * NN / 256, 256, 0, stream>>>(xyz, pts, xyz4, pts4);
  k_fps<<<BB, 512, 0, stream>>>(xyz, out);
  if (use4) {
    k_knn_blk<<<BB * SS, 256, 0, stream>>>(xyz4, kp, knn);
    k_mlp<1><<<dim3(BB * 64, 4), 256, 0, stream>>>(xyz, pts, xyz4, pts4, kp, knn,
                                                   sa_W1, sa_b1, sa_W2, sa_b2,
                                                   ms_W1, ms_b1, ms_W2, ms_b2, out);
  } else {
    k_knn_solo<<<(BB * SS) / 4, 256, 0, stream>>>(xyz, kp, knn);
    k_mlp<0><<<dim3(BB * 64, 4), 256, 0, stream>>>(xyz, pts, xyz4, pts4, kp, knn,
                                                   sa_W1, sa_b1, sa_W2, sa_b2,
                                                   ms_W1, ms_b1, ms_W2, ms_b2, out);
  }
}